// Round 2
// baseline (407.121 us; speedup 1.0000x reference)
//
#include <hip/hip_runtime.h>

#define F_IN 128
#define HID  64
#define NCLS 16
#define PADM 8   // CSR rows padded to multiple of 8 with sentinel src = N (zero row)

typedef __attribute__((ext_vector_type(2))) float f32x2;
typedef __attribute__((ext_vector_type(8))) short bf16x8;
typedef __attribute__((ext_vector_type(4))) float f32x4;

// round-to-nearest-even fp32 -> bf16
__device__ __forceinline__ unsigned short f2bf(float f) {
    unsigned int u = __float_as_uint(f);
    u += 0x7FFFu + ((u >> 16) & 1u);
    return (unsigned short)(u >> 16);
}
// one dword = 2 packed bf16 -> f32x2 (2 VALU + lets compiler use v_pk_add_f32)
__device__ __forceinline__ f32x2 bfpair(unsigned int u) {
    f32x2 r;
    r.x = __uint_as_float(u << 16);
    r.y = __uint_as_float(u & 0xFFFF0000u);
    return r;
}

// ---------- K1: zero deg, zero h2b sentinel row, build w1t (bf16 W1^T) ----------
__global__ __launch_bounds__(256) void init_kernel(int* __restrict__ deg,
        const float* __restrict__ W1, unsigned short* __restrict__ w1t,
        unsigned short* __restrict__ h2b, int N, int nzb) {
    int tid = threadIdx.x;
    if ((int)blockIdx.x == nzb) {           // fused W1 -> bf16 transpose block
        for (int i = tid; i < F_IN * HID; i += 256) {
            int k = i >> 6, nn = i & 63;
            w1t[nn * F_IN + k] = f2bf(W1[i]);
        }
        if (tid < NCLS) h2b[(size_t)N * NCLS + tid] = 0;   // sentinel row for agg2
        return;
    }
    int i = (blockIdx.x * 256 + tid) * 4;
    if (i + 3 < N) {
        *(int4*)&deg[i] = make_int4(0, 0, 0, 0);
    } else {
        for (int t = 0; t < 4; t++)
            if (i + t < N) deg[i + t] = 0;
    }
}

// ---------- K2: in-degree histogram via global atomics ----------
__global__ __launch_bounds__(256) void deg_kernel(const int* __restrict__ dst,
                                                  int* __restrict__ deg, int E) {
    int i = (blockIdx.x * 256 + threadIdx.x) * 4;
    if (i + 3 < E) {
        int4 d = *(const int4*)&dst[i];
        atomicAdd(&deg[d.x], 1);
        atomicAdd(&deg[d.y], 1);
        atomicAdd(&deg[d.z], 1);
        atomicAdd(&deg[d.w], 1);
    } else {
        for (int t = 0; t < 4; t++)
            if (i + t < E) atomicAdd(&deg[dst[i + t]], 1);
    }
}

// ---------- K3: per-256-node-block sum of padded degrees ----------
__global__ __launch_bounds__(256) void blocksum_kernel(const int* __restrict__ deg,
        int* __restrict__ bsum, int N) {
    __shared__ int red[256];
    int n = blockIdx.x * 256 + threadIdx.x;
    int dg = (n < N) ? deg[n] : 0;
    red[threadIdx.x] = (dg + PADM - 1) & ~(PADM - 1);
    __syncthreads();
    for (int o = 128; o > 0; o >>= 1) {
        if (threadIdx.x < o) red[threadIdx.x] += red[threadIdx.x + o];
        __syncthreads();
    }
    if (threadIdx.x == 0) bsum[blockIdx.x] = red[0];
}

// ---------- K4: fused global scan (redundant per block) + local scan ->
//              row_ptr (padded), cursor (into deg array), dis, CSR pad sentinels ----------
__global__ __launch_bounds__(256) void scan_kernel(int* __restrict__ deg,
        const int* __restrict__ bsum, int* __restrict__ row_ptr,
        float* __restrict__ dis, int* __restrict__ csr_src, int N, int NB) {
    __shared__ int sa[512], sb[512];
    int tid = threadIdx.x;
    int b = blockIdx.x;
    sa[tid] = (tid < NB) ? bsum[tid] : 0;
    sa[tid + 256] = (tid + 256 < NB) ? bsum[tid + 256] : 0;
    __syncthreads();
    int* s = sa;
    int* d = sb;
    for (int off = 1; off < 512; off <<= 1) {   // Hillis-Steele over 512, 2/thread
        int i0 = tid, i1 = tid + 256;
        int v0 = s[i0] + ((i0 >= off) ? s[i0 - off] : 0);
        int v1 = s[i1] + ((i1 >= off) ? s[i1 - off] : 0);
        d[i0] = v0;
        d[i1] = v1;
        __syncthreads();
        int* t = s; s = d; d = t;
    }
    int base = (b > 0) ? s[b - 1] : 0;          // exclusive prefix for this block
    int total = s[NB - 1];
    __syncthreads();                            // before buffer reuse

    int n = b * 256 + tid;
    int dg = (n < N) ? deg[n] : 0;
    int pd = (dg + PADM - 1) & ~(PADM - 1);
    s = sa; d = sb;
    s[tid] = pd;
    __syncthreads();
    for (int off = 1; off < 256; off <<= 1) {
        int v = s[tid] + ((tid >= off) ? s[tid - off] : 0);
        d[tid] = v;
        __syncthreads();
        int* t = s; s = d; d = t;
    }
    int start = base + s[tid] - pd;             // exclusive padded offset
    if (n < N) {
        row_ptr[n] = start;
        deg[n] = start;                         // becomes scatter cursor
        dis[n] = (dg > 0) ? rsqrtf(fmaxf((float)dg, 1.0f)) : 0.0f;
        for (int i = start + dg; i < start + pd; i++) csr_src[i] = N;  // pad sentinels
    }
    if (b == 0 && tid == 0) row_ptr[N] = total;
}

// ---------- K5: direct scatter into padded CSR via atomic cursors ----------
__global__ __launch_bounds__(256) void scatter_direct(const int* __restrict__ src,
        const int* __restrict__ dst, int* __restrict__ cur,
        int* __restrict__ csr_src, int E) {
    int i = (blockIdx.x * 256 + threadIdx.x) * 4;
    if (i + 3 < E) {
        int4 s4 = *(const int4*)&src[i];
        int4 d4 = *(const int4*)&dst[i];
        int p0 = atomicAdd(&cur[d4.x], 1); csr_src[p0] = s4.x;
        int p1 = atomicAdd(&cur[d4.y], 1); csr_src[p1] = s4.y;
        int p2 = atomicAdd(&cur[d4.z], 1); csr_src[p2] = s4.z;
        int p3 = atomicAdd(&cur[d4.w], 1); csr_src[p3] = s4.w;
    } else {
        for (int t = 0; t < 4; t++)
            if (i + t < E) {
                int p = atomicAdd(&cur[dst[i + t]], 1);
                csr_src[p] = src[i + t];
            }
    }
}

// ---------- gemm1 via MFMA bf16: 64 rows/block; also emits zeroed row N ----------
__global__ __launch_bounds__(256) void gemm1_kernel(
        const float* __restrict__ x, const unsigned short* __restrict__ w1t,
        const float* __restrict__ dis, unsigned short* __restrict__ h1b, int N) {
    __shared__ unsigned short xs[64][136];
    __shared__ unsigned short wsb[64][136];
    __shared__ float diss[64];
    int tid = threadIdx.x;
    int w = tid >> 6;
    int lane = tid & 63;
    int row0 = blockIdx.x * 64;

    #pragma unroll
    for (int it = 0; it < 8; it++) {
        int f = it * 256 + tid;
        int r = f >> 5, c = f & 31;
        float4 v = make_float4(0.f, 0.f, 0.f, 0.f);
        if (row0 + r < N) v = ((const float4*)x)[(size_t)(row0 + r) * 32 + c];
        unsigned int p0 = (unsigned int)f2bf(v.x) | ((unsigned int)f2bf(v.y) << 16);
        unsigned int p1 = (unsigned int)f2bf(v.z) | ((unsigned int)f2bf(v.w) << 16);
        *(uint2*)&xs[r][c * 4] = make_uint2(p0, p1);
    }
    #pragma unroll
    for (int it = 0; it < 4; it++) {
        int f = it * 256 + tid;
        int r = f >> 4, c = f & 15;
        *(uint4*)&wsb[r][c * 8] = ((const uint4*)w1t)[f];
    }
    if (tid < 64) diss[tid] = (row0 + tid < N) ? dis[row0 + tid] : 0.f;
    __syncthreads();

    int q = lane >> 4;
    int l15 = lane & 15;
    f32x4 acc[4] = {{0,0,0,0},{0,0,0,0},{0,0,0,0},{0,0,0,0}};
    bf16x8 a[4];
    #pragma unroll
    for (int kk = 0; kk < 4; kk++)
        a[kk] = *(const bf16x8*)&xs[w * 16 + l15][kk * 32 + q * 8];
    #pragma unroll
    for (int kk = 0; kk < 4; kk++) {
        #pragma unroll
        for (int ct = 0; ct < 4; ct++) {
            bf16x8 b = *(const bf16x8*)&wsb[ct * 16 + l15][kk * 32 + q * 8];
            acc[ct] = __builtin_amdgcn_mfma_f32_16x16x32_bf16(a[kk], b, acc[ct], 0, 0, 0);
        }
    }
    __syncthreads();
    #pragma unroll
    for (int ct = 0; ct < 4; ct++) {
        #pragma unroll
        for (int r = 0; r < 4; r++) {
            int m = w * 16 + q * 4 + r;
            xs[m][ct * 16 + l15] = f2bf(acc[ct][r] * diss[m]);
        }
    }
    __syncthreads();
    #pragma unroll
    for (int it = 0; it < 2; it++) {
        int f = it * 256 + tid;
        int r = f >> 3, c = f & 7;
        if (row0 + r < N + 1)   // row N written as zeros (diss=0) -> gather sentinel
            ((uint4*)&h1b[(size_t)(row0 + r) * HID])[c] = *(const uint4*)&xs[r][c * 8];
    }
}

// ---------- fused layer-1 agg + ReLU + W2 GEMM ----------
// 1 node/wave, 8 edge slots x 8 dim-lanes, mask-free padded loop, 16B gathers
__global__ __launch_bounds__(256) void agg1_fused(
        const int* __restrict__ row_ptr, const int* __restrict__ csr_src,
        const unsigned short* __restrict__ h1b, const float* __restrict__ dis,
        const float* __restrict__ b1, const float* __restrict__ W2,
        unsigned short* __restrict__ h2b, int N) {
    __shared__ float W2t[NCLS][HID + 4];   // transposed, padded row stride 68
    __shared__ float ts[4][HID];
    int tid = threadIdx.x;
    for (int i = tid; i < HID * NCLS; i += 256) W2t[i & 15][i >> 4] = W2[i];
    __syncthreads();

    int w = tid >> 6;
    int lane = tid & 63;
    int sub = lane & 7;        // dims sub*8 .. sub*8+7 (16B)
    int slot = lane >> 3;      // edge slot 0..7
    int n = blockIdx.x * 4 + w;
    if (n >= N) return;        // wave-uniform exit (after the only __syncthreads)
    float dn = dis[n];
    int beg = row_ptr[n];
    int end = row_ptr[n + 1];  // padded: (end-beg) % 8 == 0, uniform trip count

    f32x2 a0 = {0.f, 0.f}, a1 = a0, a2 = a0, a3 = a0;
    const unsigned short* hp = h1b + sub * 8;
    for (int i = beg + slot; i < end; i += 8) {
        int s = csr_src[i];                             // sentinel N -> zero row
        uint4 v = *(const uint4*)(hp + (unsigned)s * HID);
        a0 += bfpair(v.x);
        a1 += bfpair(v.y);
        a2 += bfpair(v.z);
        a3 += bfpair(v.w);
    }
    // reduce across 8 slots (lane bits 3,4,5)
    #pragma unroll
    for (int m = 8; m <= 32; m <<= 1) {
        a0.x += __shfl_xor(a0.x, m, 64); a0.y += __shfl_xor(a0.y, m, 64);
        a1.x += __shfl_xor(a1.x, m, 64); a1.y += __shfl_xor(a1.y, m, 64);
        a2.x += __shfl_xor(a2.x, m, 64); a2.y += __shfl_xor(a2.y, m, 64);
        a3.x += __shfl_xor(a3.x, m, 64); a3.y += __shfl_xor(a3.y, m, 64);
    }
    if (slot == 0) {
        float4 bl = ((const float4*)b1)[sub * 2];
        float4 bh = ((const float4*)b1)[sub * 2 + 1];
        float4 r0, r1;
        r0.x = fmaxf(fmaf(dn, a0.x, bl.x), 0.f);
        r0.y = fmaxf(fmaf(dn, a0.y, bl.y), 0.f);
        r0.z = fmaxf(fmaf(dn, a1.x, bl.z), 0.f);
        r0.w = fmaxf(fmaf(dn, a1.y, bl.w), 0.f);
        r1.x = fmaxf(fmaf(dn, a2.x, bh.x), 0.f);
        r1.y = fmaxf(fmaf(dn, a2.y, bh.y), 0.f);
        r1.z = fmaxf(fmaf(dn, a3.x, bh.z), 0.f);
        r1.w = fmaxf(fmaf(dn, a3.y, bh.w), 0.f);
        *(float4*)&ts[w][sub * 8] = r0;
        *(float4*)&ts[w][sub * 8 + 4] = r1;
    }
    // wave-local LDS round-trip (same wave writes+reads; compiler inserts lgkmcnt)
    int q = lane >> 4, c = lane & 15;
    const float* tp = &ts[w][q * 16];
    const float* wp = &W2t[c][q * 16];
    float4 t0 = *(const float4*)tp,       t1 = *(const float4*)(tp + 4);
    float4 t2 = *(const float4*)(tp + 8), t3 = *(const float4*)(tp + 12);
    float4 u0 = *(const float4*)wp,       u1 = *(const float4*)(wp + 4);
    float4 u2 = *(const float4*)(wp + 8), u3 = *(const float4*)(wp + 12);
    float p = t0.x * u0.x + t0.y * u0.y + t0.z * u0.z + t0.w * u0.w
            + t1.x * u1.x + t1.y * u1.y + t1.z * u1.z + t1.w * u1.w
            + t2.x * u2.x + t2.y * u2.y + t2.z * u2.z + t2.w * u2.w
            + t3.x * u3.x + t3.y * u3.y + t3.z * u3.z + t3.w * u3.w;
    p += __shfl_xor(p, 16, 64);
    p += __shfl_xor(p, 32, 64);
    if (lane < 16) h2b[(unsigned)n * NCLS + c] = f2bf(p * dn);
}

// ---------- fused layer-2 agg + epilogue ----------
// 4 nodes/wave, 8 edge slots x 2 dim-lanes (16B), mask-free padded loop
__global__ __launch_bounds__(256) void agg2_fused(
        const int* __restrict__ row_ptr, const int* __restrict__ csr_src,
        const unsigned short* __restrict__ h2b, const float* __restrict__ dis,
        const float* __restrict__ b2, float* __restrict__ out, int N) {
    int t = blockIdx.x * 256 + threadIdx.x;
    int lane = t & 63;
    int grp = lane >> 4;         // node within wave
    int slot = (lane >> 1) & 7;  // edge slot
    int sub = lane & 1;          // dims sub*8 .. sub*8+7
    int n = (t >> 6) * 4 + grp;
    if (n >= N) return;          // uniform within each 16-lane group
    int beg = row_ptr[n];
    int end = row_ptr[n + 1];

    f32x2 a0 = {0.f, 0.f}, a1 = a0, a2 = a0, a3 = a0;
    const unsigned short* hp = h2b + sub * 8;
    for (int i = beg + slot; i < end; i += 8) {
        int s = csr_src[i];
        uint4 v = *(const uint4*)(hp + (unsigned)s * NCLS);
        a0 += bfpair(v.x);
        a1 += bfpair(v.y);
        a2 += bfpair(v.z);
        a3 += bfpair(v.w);
    }
    // reduce across 8 slots (lane bits 1,2,3 — stays inside the 16-lane group)
    #pragma unroll
    for (int m = 2; m <= 8; m <<= 1) {
        a0.x += __shfl_xor(a0.x, m, 64); a0.y += __shfl_xor(a0.y, m, 64);
        a1.x += __shfl_xor(a1.x, m, 64); a1.y += __shfl_xor(a1.y, m, 64);
        a2.x += __shfl_xor(a2.x, m, 64); a2.y += __shfl_xor(a2.y, m, 64);
        a3.x += __shfl_xor(a3.x, m, 64); a3.y += __shfl_xor(a3.y, m, 64);
    }
    if (slot == 0) {
        float dn = dis[n];
        float4 bl = ((const float4*)b2)[sub * 2];
        float4 bh = ((const float4*)b2)[sub * 2 + 1];
        float4 o0, o1;
        o0.x = fmaf(dn, a0.x, bl.x); o0.y = fmaf(dn, a0.y, bl.y);
        o0.z = fmaf(dn, a1.x, bl.z); o0.w = fmaf(dn, a1.y, bl.w);
        o1.x = fmaf(dn, a2.x, bh.x); o1.y = fmaf(dn, a2.y, bh.y);
        o1.z = fmaf(dn, a3.x, bh.z); o1.w = fmaf(dn, a3.y, bh.w);
        float* op = out + (unsigned)n * NCLS + sub * 8;
        *(float4*)op = o0;
        *(float4*)(op + 4) = o1;
    }
}

extern "C" void kernel_launch(void* const* d_in, const int* in_sizes, int n_in,
                              void* d_out, int out_size, void* d_ws, size_t ws_size,
                              hipStream_t stream) {
    const float* x   = (const float*)d_in[0];
    const int*   src = (const int*)  d_in[1];
    const int*   dst = (const int*)  d_in[2];
    const float* W1  = (const float*)d_in[3];
    const float* b1  = (const float*)d_in[4];
    const float* W2  = (const float*)d_in[5];
    const float* b2  = (const float*)d_in[6];
    float* out = (float*)d_out;
    int E = in_sizes[1];
    int N = in_sizes[0] / F_IN;
    int NB = (N + 255) >> 8;                  // <= 512 for N <= 128k

    char* ws = (char*)d_ws;
    size_t off = 0;
    auto alloc = [&](size_t bytes) { size_t o = off; off = (off + bytes + 255) & ~(size_t)255; return (void*)(ws + o); };
    int*   bsum    = (int*)  alloc(512 * 4);
    int*   row_ptr = (int*)  alloc((size_t)(N + 1) * 4);
    float* dis     = (float*)alloc((size_t)N * 4);
    unsigned short* w1t = (unsigned short*)alloc((size_t)F_IN * HID * 2);
    int*   csr_src = (int*)  alloc(((size_t)E + (size_t)(PADM - 1) * N + 64) * 4);
    unsigned short* h1b = (unsigned short*)alloc((size_t)(N + 1) * HID * 2);
    unsigned short* h2b = (unsigned short*)alloc((size_t)(N + 1) * NCLS * 2);
    // deg/cursor aliases the head of h1b: dead after scatter_direct, before gemm1
    int* deg = (int*)h1b;

    int nzb = (N + 1023) / 1024;
    int geb = (E + 1023) / 1024;

    init_kernel    <<<nzb + 1, 256, 0, stream>>>(deg, W1, w1t, h2b, N, nzb);
    deg_kernel     <<<geb, 256, 0, stream>>>(dst, deg, E);
    blocksum_kernel<<<NB, 256, 0, stream>>>(deg, bsum, N);
    scan_kernel    <<<NB, 256, 0, stream>>>(deg, bsum, row_ptr, dis, csr_src, N, NB);
    scatter_direct <<<geb, 256, 0, stream>>>(src, dst, deg, csr_src, E);
    gemm1_kernel   <<<(N + 64) / 64, 256, 0, stream>>>(x, w1t, dis, h1b, N);
    agg1_fused     <<<(N + 3) / 4, 256, 0, stream>>>(row_ptr, csr_src, h1b, dis, b1, W2, h2b, N);
    agg2_fused     <<<(N + 15) / 16, 256, 0, stream>>>(row_ptr, csr_src, h2b, dis, b2, out, N);
}

// Round 3
// 236.659 us; speedup vs baseline: 1.7203x; 1.7203x over previous
//
#include <hip/hip_runtime.h>

#define F_IN 128
#define HID  64
#define NCLS 16

#define BSHIFT 8            // 256 nodes per bucket
#define BNODES 256
#define NB_MAX 512          // max buckets (N<=128k)
#define CHUNK  8192         // edges per partition block (nchunks must be <=256 for col_scan)
#define CAP    8192         // max edges per bucket in LDS (mean 4352, 50+ sigma margin)

typedef __attribute__((ext_vector_type(2))) float f32x2;
typedef __attribute__((ext_vector_type(8))) short bf16x8;
typedef __attribute__((ext_vector_type(4))) float f32x4;

// round-to-nearest-even fp32 -> bf16
__device__ __forceinline__ unsigned short f2bf(float f) {
    unsigned int u = __float_as_uint(f);
    u += 0x7FFFu + ((u >> 16) & 1u);
    return (unsigned short)(u >> 16);
}
// one dword = 2 packed bf16 -> f32x2 (2 VALU unpack + packed add)
__device__ __forceinline__ f32x2 bfpair(unsigned int u) {
    f32x2 r;
    r.x = __uint_as_float(u << 16);
    r.y = __uint_as_float(u & 0xFFFF0000u);
    return r;
}

// ---------- pass 1: per-block bucket histogram (non-atomic global) + fused w1t ----------
__global__ __launch_bounds__(256) void hist_w1t_kernel(const int* __restrict__ dst,
                                                       int* __restrict__ blk_hist,
                                                       const float* __restrict__ W1,
                                                       unsigned short* __restrict__ w1t,
                                                       int E, int NB, int nchunks) {
    int blk = blockIdx.x;
    int tid = threadIdx.x;
    if (blk == nchunks) {           // fused W1 -> bf16 transpose block
        for (int i = tid; i < F_IN * HID; i += 256) {
            int k = i >> 6, n = i & 63;
            w1t[n * F_IN + k] = f2bf(W1[i]);
        }
        return;
    }
    __shared__ int hist[NB_MAX];
    for (int i = tid; i < NB; i += 256) hist[i] = 0;
    __syncthreads();
    int cb = blk * CHUNK;
    #pragma unroll
    for (int k = 0; k < CHUNK / 1024; k++) {
        int e = cb + (k * 256 + tid) * 4;
        if (e + 3 < E) {
            int4 d4 = *(const int4*)&dst[e];
            atomicAdd(&hist[d4.x >> BSHIFT], 1);
            atomicAdd(&hist[d4.y >> BSHIFT], 1);
            atomicAdd(&hist[d4.z >> BSHIFT], 1);
            atomicAdd(&hist[d4.w >> BSHIFT], 1);
        } else {
            for (int t = 0; t < 4; t++)
                if (e + t < E) atomicAdd(&hist[dst[e + t] >> BSHIFT], 1);
        }
    }
    __syncthreads();
    for (int i = tid; i < NB; i += 256) blk_hist[(size_t)blk * NB + i] = hist[i];
}

// ---------- pass 2a: parallel column reduce -> bucket totals ----------
__global__ __launch_bounds__(256) void col_reduce(const int* __restrict__ blk_hist,
                                                  int* __restrict__ bucket_count,
                                                  int NB, int nchunks) {
    __shared__ int red[256];
    int b = blockIdx.x;
    int tid = threadIdx.x;
    int s = 0;
    for (int j = tid; j < nchunks; j += 256) s += blk_hist[(size_t)j * NB + b];
    red[tid] = s;
    __syncthreads();
    for (int off = 128; off > 0; off >>= 1) {
        if (tid < off) red[tid] += red[tid + off];
        __syncthreads();
    }
    if (tid == 0) bucket_count[b] = red[0];
}

// ---------- pass 2b: single-block scan of bucket totals -> bases ----------
__global__ __launch_bounds__(512) void scan_small(const int* __restrict__ bucket_count,
                                                  int* __restrict__ bucket_base,
                                                  int* __restrict__ row_ptr,
                                                  int NB, int N, int E) {
    __shared__ int s[512];
    int tid = threadIdx.x;
    int v = (tid < NB) ? bucket_count[tid] : 0;
    s[tid] = v;
    __syncthreads();
    for (int off = 1; off < 512; off <<= 1) {
        int t = (tid >= off) ? s[tid - off] : 0;
        __syncthreads();
        s[tid] += t;
        __syncthreads();
    }
    if (tid < NB) bucket_base[tid] = s[tid] - v;
    if (tid == 0) { bucket_base[NB] = E; row_ptr[N] = E; }
}

// ---------- pass 2c: per-bucket parallel column scan -> absolute per-chunk bases ----------
__global__ __launch_bounds__(256) void col_scan(int* __restrict__ blk_hist,
                                                const int* __restrict__ bucket_base,
                                                int NB, int nchunks) {
    __shared__ int s[256];
    int b = blockIdx.x;
    int tid = threadIdx.x;
    int v = (tid < nchunks) ? blk_hist[(size_t)tid * NB + b] : 0;
    s[tid] = v;
    __syncthreads();
    for (int off = 1; off < 256; off <<= 1) {
        int t = (tid >= off) ? s[tid - off] : 0;
        __syncthreads();
        s[tid] += t;
        __syncthreads();
    }
    if (tid < nchunks) blk_hist[(size_t)tid * NB + b] = s[tid] - v + bucket_base[b];
}

// ---------- pass 3: single-pass partition (LDS cursors, coalesced per-bucket runs) ----------
__global__ __launch_bounds__(256) void scatter_kernel(const int* __restrict__ src,
                                                      const int* __restrict__ dst,
                                                      const int* __restrict__ blk_hist,
                                                      unsigned int* __restrict__ part,
                                                      int E, int NB) {
    __shared__ int cur[NB_MAX];
    int tid = threadIdx.x;
    int blk = blockIdx.x;
    for (int i = tid; i < NB; i += 256) cur[i] = blk_hist[(size_t)blk * NB + i];
    __syncthreads();
    int cb = blk * CHUNK;
    #pragma unroll
    for (int k = 0; k < CHUNK / 1024; k++) {
        int e = cb + (k * 256 + tid) * 4;
        if (e + 3 < E) {
            int4 d4 = *(const int4*)&dst[e];
            int4 s4 = *(const int4*)&src[e];
            int p0 = atomicAdd(&cur[d4.x >> BSHIFT], 1);
            part[p0] = ((unsigned int)(d4.x & (BNODES - 1)) << 24) | (unsigned int)s4.x;
            int p1 = atomicAdd(&cur[d4.y >> BSHIFT], 1);
            part[p1] = ((unsigned int)(d4.y & (BNODES - 1)) << 24) | (unsigned int)s4.y;
            int p2 = atomicAdd(&cur[d4.z >> BSHIFT], 1);
            part[p2] = ((unsigned int)(d4.z & (BNODES - 1)) << 24) | (unsigned int)s4.z;
            int p3 = atomicAdd(&cur[d4.w >> BSHIFT], 1);
            part[p3] = ((unsigned int)(d4.w & (BNODES - 1)) << 24) | (unsigned int)s4.w;
        } else {
            for (int t = 0; t < 4; t++)
                if (e + t < E) {
                    int d = dst[e + t];
                    int pos = atomicAdd(&cur[d >> BSHIFT], 1);
                    part[pos] = ((unsigned int)(d & (BNODES - 1)) << 24) | (unsigned int)src[e + t];
                }
        }
    }
}

// ---------- pass 4: per-bucket counting sort -> csr_src, row_ptr, dis ----------
__global__ __launch_bounds__(256) void csr_build(const unsigned int* __restrict__ part,
                                                 const int* __restrict__ bucket_base,
                                                 int* __restrict__ csr_src,
                                                 int* __restrict__ row_ptr,
                                                 float* __restrict__ dis,
                                                 int N) {
    __shared__ unsigned int eL[CAP];
    __shared__ unsigned int outL[CAP];
    __shared__ int cnt[BNODES];
    __shared__ int sc[BNODES];
    __shared__ int cur[BNODES];
    int tid = threadIdx.x;
    int b = blockIdx.x;
    int eB = bucket_base[b];
    int eN = bucket_base[b + 1] - eB;
    if (eN > CAP) eN = CAP;

    cnt[tid] = 0;
    __syncthreads();
    for (int i = tid; i < eN; i += 256) {
        unsigned int v = part[eB + i];
        eL[i] = v;
        atomicAdd(&cnt[v >> 24], 1);
    }
    __syncthreads();
    int myc = cnt[tid];
    sc[tid] = myc;
    __syncthreads();
    for (int off = 1; off < 256; off <<= 1) {
        int t = (tid >= off) ? sc[tid - off] : 0;
        __syncthreads();
        sc[tid] += t;
        __syncthreads();
    }
    int excl = sc[tid] - myc;
    cur[tid] = excl;
    int gnode = b * BNODES + tid;
    if (gnode < N) {
        row_ptr[gnode] = eB + excl;
        float d = (float)myc;
        dis[gnode] = d > 0.0f ? rsqrtf(fmaxf(d, 1.0f)) : 0.0f;
    }
    __syncthreads();
    for (int i = tid; i < eN; i += 256) {
        unsigned int v = eL[i];
        int pos = atomicAdd(&cur[v >> 24], 1);
        outL[pos] = v & 0xFFFFFFu;
    }
    __syncthreads();
    for (int i = tid; i < eN; i += 256)
        csr_src[eB + i] = (int)outL[i];
}

// ---------- gemm1 via MFMA bf16: 64 rows/block, 4 waves x (16 rows x 64 cols) ----------
__global__ __launch_bounds__(256) void gemm1_kernel(
        const float* __restrict__ x, const unsigned short* __restrict__ w1t,
        const float* __restrict__ dis, unsigned short* __restrict__ h1b, int N) {
    __shared__ unsigned short xs[64][136];
    __shared__ unsigned short wsb[64][136];
    __shared__ float diss[64];
    int tid = threadIdx.x;
    int w = tid >> 6;
    int lane = tid & 63;
    int row0 = blockIdx.x * 64;

    #pragma unroll
    for (int it = 0; it < 8; it++) {
        int f = it * 256 + tid;
        int r = f >> 5, c = f & 31;
        float4 v = make_float4(0.f, 0.f, 0.f, 0.f);
        if (row0 + r < N) v = ((const float4*)x)[(size_t)(row0 + r) * 32 + c];
        unsigned int p0 = (unsigned int)f2bf(v.x) | ((unsigned int)f2bf(v.y) << 16);
        unsigned int p1 = (unsigned int)f2bf(v.z) | ((unsigned int)f2bf(v.w) << 16);
        *(uint2*)&xs[r][c * 4] = make_uint2(p0, p1);
    }
    #pragma unroll
    for (int it = 0; it < 4; it++) {
        int f = it * 256 + tid;
        int r = f >> 4, c = f & 15;
        *(uint4*)&wsb[r][c * 8] = ((const uint4*)w1t)[f];
    }
    if (tid < 64) diss[tid] = (row0 + tid < N) ? dis[row0 + tid] : 0.f;
    __syncthreads();

    int q = lane >> 4;
    int l15 = lane & 15;
    f32x4 acc[4] = {{0,0,0,0},{0,0,0,0},{0,0,0,0},{0,0,0,0}};
    bf16x8 a[4];
    #pragma unroll
    for (int kk = 0; kk < 4; kk++)
        a[kk] = *(const bf16x8*)&xs[w * 16 + l15][kk * 32 + q * 8];
    #pragma unroll
    for (int kk = 0; kk < 4; kk++) {
        #pragma unroll
        for (int ct = 0; ct < 4; ct++) {
            bf16x8 b = *(const bf16x8*)&wsb[ct * 16 + l15][kk * 32 + q * 8];
            acc[ct] = __builtin_amdgcn_mfma_f32_16x16x32_bf16(a[kk], b, acc[ct], 0, 0, 0);
        }
    }
    __syncthreads();
    #pragma unroll
    for (int ct = 0; ct < 4; ct++) {
        #pragma unroll
        for (int r = 0; r < 4; r++) {
            int m = w * 16 + q * 4 + r;
            xs[m][ct * 16 + l15] = f2bf(acc[ct][r] * diss[m]);
        }
    }
    __syncthreads();
    #pragma unroll
    for (int it = 0; it < 2; it++) {
        int f = it * 256 + tid;
        int r = f >> 3, c = f & 7;
        if (row0 + r < N)
            ((uint4*)&h1b[(size_t)(row0 + r) * HID])[c] = *(const uint4*)&xs[r][c * 8];
    }
}

// ---------- fused layer-1 agg + ReLU + W2 GEMM ----------
// 1 node/wave, 8 edge slots x 8 dim-lanes, 16B gathers, exec-masked tail (no clamps)
__global__ __launch_bounds__(256) void agg1_fused(
        const int* __restrict__ row_ptr, const int* __restrict__ csr_src,
        const unsigned short* __restrict__ h1b, const float* __restrict__ dis,
        const float* __restrict__ b1, const float* __restrict__ W2,
        unsigned short* __restrict__ h2b, int N) {
    __shared__ float W2t[NCLS][HID + 4];   // transposed, padded row stride 68
    __shared__ float ts[4][HID];
    int tid = threadIdx.x;
    for (int i = tid; i < HID * NCLS; i += 256) W2t[i & 15][i >> 4] = W2[i];
    __syncthreads();

    int w = tid >> 6;
    int lane = tid & 63;
    int sub = lane & 7;        // dims sub*8 .. sub*8+7 (16B)
    int slot = lane >> 3;      // edge slot 0..7
    int n = blockIdx.x * 4 + w;
    if (n >= N) return;        // wave-uniform exit (after the only __syncthreads)
    float dn = dis[n];
    int beg = row_ptr[n];
    int end = row_ptr[n + 1];

    f32x2 a0 = {0.f, 0.f}, a1 = a0, a2 = a0, a3 = a0;
    const unsigned short* hp = h1b + sub * 8;
    for (int i = beg + slot; i < end; i += 8) {   // divergent tail: exec mask, no clamps
        int s = csr_src[i];
        uint4 v = *(const uint4*)(hp + (unsigned)s * HID);
        a0 += bfpair(v.x);
        a1 += bfpair(v.y);
        a2 += bfpair(v.z);
        a3 += bfpair(v.w);
    }
    // reduce across 8 slots (lane bits 3,4,5)
    #pragma unroll
    for (int m = 8; m <= 32; m <<= 1) {
        a0.x += __shfl_xor(a0.x, m, 64); a0.y += __shfl_xor(a0.y, m, 64);
        a1.x += __shfl_xor(a1.x, m, 64); a1.y += __shfl_xor(a1.y, m, 64);
        a2.x += __shfl_xor(a2.x, m, 64); a2.y += __shfl_xor(a2.y, m, 64);
        a3.x += __shfl_xor(a3.x, m, 64); a3.y += __shfl_xor(a3.y, m, 64);
    }
    if (slot == 0) {
        float4 bl = ((const float4*)b1)[sub * 2];
        float4 bh = ((const float4*)b1)[sub * 2 + 1];
        float4 r0, r1;
        r0.x = fmaxf(fmaf(dn, a0.x, bl.x), 0.f);
        r0.y = fmaxf(fmaf(dn, a0.y, bl.y), 0.f);
        r0.z = fmaxf(fmaf(dn, a1.x, bl.z), 0.f);
        r0.w = fmaxf(fmaf(dn, a1.y, bl.w), 0.f);
        r1.x = fmaxf(fmaf(dn, a2.x, bh.x), 0.f);
        r1.y = fmaxf(fmaf(dn, a2.y, bh.y), 0.f);
        r1.z = fmaxf(fmaf(dn, a3.x, bh.z), 0.f);
        r1.w = fmaxf(fmaf(dn, a3.y, bh.w), 0.f);
        *(float4*)&ts[w][sub * 8] = r0;
        *(float4*)&ts[w][sub * 8 + 4] = r1;
    }
    // wave-local LDS round-trip (same wave writes+reads; compiler inserts lgkmcnt)
    int q = lane >> 4, c = lane & 15;
    const float* tp = &ts[w][q * 16];
    const float* wp = &W2t[c][q * 16];
    float4 t0 = *(const float4*)tp,       t1 = *(const float4*)(tp + 4);
    float4 t2 = *(const float4*)(tp + 8), t3 = *(const float4*)(tp + 12);
    float4 u0 = *(const float4*)wp,       u1 = *(const float4*)(wp + 4);
    float4 u2 = *(const float4*)(wp + 8), u3 = *(const float4*)(wp + 12);
    float p = t0.x * u0.x + t0.y * u0.y + t0.z * u0.z + t0.w * u0.w
            + t1.x * u1.x + t1.y * u1.y + t1.z * u1.z + t1.w * u1.w
            + t2.x * u2.x + t2.y * u2.y + t2.z * u2.z + t2.w * u2.w
            + t3.x * u3.x + t3.y * u3.y + t3.z * u3.z + t3.w * u3.w;
    p += __shfl_xor(p, 16, 64);
    p += __shfl_xor(p, 32, 64);
    if (lane < 16) h2b[(unsigned)n * NCLS + c] = f2bf(p * dn);
}

// ---------- fused layer-2 agg + epilogue ----------
// 4 nodes/wave, 8 edge slots x 2 dim-lanes (16B), exec-masked tail
__global__ __launch_bounds__(256) void agg2_fused(
        const int* __restrict__ row_ptr, const int* __restrict__ csr_src,
        const unsigned short* __restrict__ h2b, const float* __restrict__ dis,
        const float* __restrict__ b2, float* __restrict__ out, int N) {
    int t = blockIdx.x * 256 + threadIdx.x;
    int lane = t & 63;
    int grp = lane >> 4;         // node within wave
    int slot = (lane >> 1) & 7;  // edge slot
    int sub = lane & 1;          // dims sub*8 .. sub*8+7
    int n = (t >> 6) * 4 + grp;
    if (n >= N) return;          // uniform within each 16-lane group
    int beg = row_ptr[n];
    int end = row_ptr[n + 1];

    f32x2 a0 = {0.f, 0.f}, a1 = a0, a2 = a0, a3 = a0;
    const unsigned short* hp = h2b + sub * 8;
    for (int i = beg + slot; i < end; i += 8) {
        int s = csr_src[i];
        uint4 v = *(const uint4*)(hp + (unsigned)s * NCLS);
        a0 += bfpair(v.x);
        a1 += bfpair(v.y);
        a2 += bfpair(v.z);
        a3 += bfpair(v.w);
    }
    // reduce across 8 slots (lane bits 1,2,3 — stays inside the 16-lane group)
    #pragma unroll
    for (int m = 2; m <= 8; m <<= 1) {
        a0.x += __shfl_xor(a0.x, m, 64); a0.y += __shfl_xor(a0.y, m, 64);
        a1.x += __shfl_xor(a1.x, m, 64); a1.y += __shfl_xor(a1.y, m, 64);
        a2.x += __shfl_xor(a2.x, m, 64); a2.y += __shfl_xor(a2.y, m, 64);
        a3.x += __shfl_xor(a3.x, m, 64); a3.y += __shfl_xor(a3.y, m, 64);
    }
    if (slot == 0) {
        float dn = dis[n];
        float4 bl = ((const float4*)b2)[sub * 2];
        float4 bh = ((const float4*)b2)[sub * 2 + 1];
        float4 o0, o1;
        o0.x = fmaf(dn, a0.x, bl.x); o0.y = fmaf(dn, a0.y, bl.y);
        o0.z = fmaf(dn, a1.x, bl.z); o0.w = fmaf(dn, a1.y, bl.w);
        o1.x = fmaf(dn, a2.x, bh.x); o1.y = fmaf(dn, a2.y, bh.y);
        o1.z = fmaf(dn, a3.x, bh.z); o1.w = fmaf(dn, a3.y, bh.w);
        float* op = out + (unsigned)n * NCLS + sub * 8;
        *(float4*)op = o0;
        *(float4*)(op + 4) = o1;
    }
}

extern "C" void kernel_launch(void* const* d_in, const int* in_sizes, int n_in,
                              void* d_out, int out_size, void* d_ws, size_t ws_size,
                              hipStream_t stream) {
    const float* x   = (const float*)d_in[0];
    const int*   src = (const int*)  d_in[1];
    const int*   dst = (const int*)  d_in[2];
    const float* W1  = (const float*)d_in[3];
    const float* b1  = (const float*)d_in[4];
    const float* W2  = (const float*)d_in[5];
    const float* b2  = (const float*)d_in[6];
    float* out = (float*)d_out;
    int E = in_sizes[1];
    int N = in_sizes[0] / F_IN;
    int NB = (N + BNODES - 1) >> BSHIFT;
    int nchunks = (E + CHUNK - 1) / CHUNK;   // 208 for E=1.7M (col_scan requires <=256)

    char* ws = (char*)d_ws;
    size_t off = 0;
    auto alloc = [&](size_t bytes) { size_t o = off; off = (off + bytes + 255) & ~(size_t)255; return (void*)(ws + o); };
    int*   bucket_count  = (int*)  alloc((size_t)NB * 4);
    int*   bucket_base   = (int*)  alloc((size_t)(NB + 1) * 4);
    int*   blk_hist      = (int*)  alloc((size_t)nchunks * NB * 4);
    int*   row_ptr       = (int*)  alloc((size_t)(N + 1) * 4);
    int*   csr_src       = (int*)  alloc((size_t)E * 4);
    float* dis           = (float*)alloc((size_t)N * 4);
    unsigned short* w1t  = (unsigned short*)alloc((size_t)F_IN * HID * 2);
    unsigned short* h1b  = (unsigned short*)alloc((size_t)N * HID * 2);
    unsigned short* h2b  = (unsigned short*)alloc((size_t)N * NCLS * 2);
    // part[] aliases h1b: dead before gemm1 writes h1b (E*4 = 6.8MB <= N*HID*2 = 12.8MB)
    unsigned int* part   = (unsigned int*)h1b;

    hist_w1t_kernel<<<nchunks + 1, 256, 0, stream>>>(dst, blk_hist, W1, w1t, E, NB, nchunks);
    col_reduce     <<<NB, 256, 0, stream>>>(blk_hist, bucket_count, NB, nchunks);
    scan_small     <<<1, 512, 0, stream>>>(bucket_count, bucket_base, row_ptr, NB, N, E);
    col_scan       <<<NB, 256, 0, stream>>>(blk_hist, bucket_base, NB, nchunks);
    scatter_kernel <<<nchunks, 256, 0, stream>>>(src, dst, blk_hist, part, E, NB);
    csr_build      <<<NB, 256, 0, stream>>>(part, bucket_base, csr_src, row_ptr, dis, N);
    gemm1_kernel   <<<(N + 63) / 64, 256, 0, stream>>>(x, w1t, dis, h1b, N);
    agg1_fused     <<<(N + 3) / 4, 256, 0, stream>>>(row_ptr, csr_src, h1b, dis, b1, W2, h2b, N);
    agg2_fused     <<<(N + 15) / 16, 256, 0, stream>>>(row_ptr, csr_src, h2b, dis, b2, out, N);
}

// Round 4
// 219.916 us; speedup vs baseline: 1.8513x; 1.0761x over previous
//
#include <hip/hip_runtime.h>

#define F_IN 128
#define HID  64
#define NCLS 16

#define BSHIFT 8            // 256 nodes per bucket
#define BNODES 256
#define NB_MAX 512          // max buckets (N<=128k)
#define CHUNK  8192         // edges per partition block (nchunks must be <=256 for col_scan)
#define CAP    8192         // max edges per bucket in LDS (mean 4352, 50+ sigma margin)

typedef __attribute__((ext_vector_type(2))) float f32x2;
typedef __attribute__((ext_vector_type(8))) short bf16x8;
typedef __attribute__((ext_vector_type(4))) float f32x4;

// round-to-nearest-even fp32 -> bf16
__device__ __forceinline__ unsigned short f2bf(float f) {
    unsigned int u = __float_as_uint(f);
    u += 0x7FFFu + ((u >> 16) & 1u);
    return (unsigned short)(u >> 16);
}
// one dword = 2 packed bf16 -> f32x2 (2 VALU unpack + packed add)
__device__ __forceinline__ f32x2 bfpair(unsigned int u) {
    f32x2 r;
    r.x = __uint_as_float(u << 16);
    r.y = __uint_as_float(u & 0xFFFF0000u);
    return r;
}

// ---------- pass 1: per-block bucket histogram (non-atomic global) + fused w1t ----------
__global__ __launch_bounds__(256) void hist_w1t_kernel(const int* __restrict__ dst,
                                                       int* __restrict__ blk_hist,
                                                       const float* __restrict__ W1,
                                                       unsigned short* __restrict__ w1t,
                                                       unsigned short* __restrict__ h2b,
                                                       int E, int N, int NB, int nchunks) {
    int blk = blockIdx.x;
    int tid = threadIdx.x;
    if (blk == nchunks) {           // fused W1 -> bf16 transpose block
        for (int i = tid; i < F_IN * HID; i += 256) {
            int k = i >> 6, n = i & 63;
            w1t[n * F_IN + k] = f2bf(W1[i]);
        }
        if (tid < NCLS) h2b[(size_t)N * NCLS + tid] = 0;   // zero sentinel row for agg2
        return;
    }
    __shared__ int hist[NB_MAX];
    for (int i = tid; i < NB; i += 256) hist[i] = 0;
    __syncthreads();
    int cb = blk * CHUNK;
    #pragma unroll
    for (int k = 0; k < CHUNK / 1024; k++) {
        int e = cb + (k * 256 + tid) * 4;
        if (e + 3 < E) {
            int4 d4 = *(const int4*)&dst[e];
            atomicAdd(&hist[d4.x >> BSHIFT], 1);
            atomicAdd(&hist[d4.y >> BSHIFT], 1);
            atomicAdd(&hist[d4.z >> BSHIFT], 1);
            atomicAdd(&hist[d4.w >> BSHIFT], 1);
        } else {
            for (int t = 0; t < 4; t++)
                if (e + t < E) atomicAdd(&hist[dst[e + t] >> BSHIFT], 1);
        }
    }
    __syncthreads();
    for (int i = tid; i < NB; i += 256) blk_hist[(size_t)blk * NB + i] = hist[i];
}

// ---------- pass 2a: parallel column reduce -> bucket totals ----------
__global__ __launch_bounds__(256) void col_reduce(const int* __restrict__ blk_hist,
                                                  int* __restrict__ bucket_count,
                                                  int NB, int nchunks) {
    __shared__ int red[256];
    int b = blockIdx.x;
    int tid = threadIdx.x;
    int s = 0;
    for (int j = tid; j < nchunks; j += 256) s += blk_hist[(size_t)j * NB + b];
    red[tid] = s;
    __syncthreads();
    for (int off = 128; off > 0; off >>= 1) {
        if (tid < off) red[tid] += red[tid + off];
        __syncthreads();
    }
    if (tid == 0) bucket_count[b] = red[0];
}

// ---------- pass 2b: single-block scan of bucket totals -> bases ----------
__global__ __launch_bounds__(512) void scan_small(const int* __restrict__ bucket_count,
                                                  int* __restrict__ bucket_base,
                                                  int* __restrict__ row_ptr,
                                                  int NB, int N, int E) {
    __shared__ int s[512];
    int tid = threadIdx.x;
    int v = (tid < NB) ? bucket_count[tid] : 0;
    s[tid] = v;
    __syncthreads();
    for (int off = 1; off < 512; off <<= 1) {
        int t = (tid >= off) ? s[tid - off] : 0;
        __syncthreads();
        s[tid] += t;
        __syncthreads();
    }
    if (tid < NB) bucket_base[tid] = s[tid] - v;
    if (tid == 0) { bucket_base[NB] = E; row_ptr[N] = E; }
}

// ---------- pass 2c: per-bucket parallel column scan -> absolute per-chunk bases ----------
__global__ __launch_bounds__(256) void col_scan(int* __restrict__ blk_hist,
                                                const int* __restrict__ bucket_base,
                                                int NB, int nchunks) {
    __shared__ int s[256];
    int b = blockIdx.x;
    int tid = threadIdx.x;
    int v = (tid < nchunks) ? blk_hist[(size_t)tid * NB + b] : 0;
    s[tid] = v;
    __syncthreads();
    for (int off = 1; off < 256; off <<= 1) {
        int t = (tid >= off) ? s[tid - off] : 0;
        __syncthreads();
        s[tid] += t;
        __syncthreads();
    }
    if (tid < nchunks) blk_hist[(size_t)tid * NB + b] = s[tid] - v + bucket_base[b];
}

// ---------- pass 3: single-pass partition (LDS cursors, coalesced per-bucket runs) ----------
__global__ __launch_bounds__(256) void scatter_kernel(const int* __restrict__ src,
                                                      const int* __restrict__ dst,
                                                      const int* __restrict__ blk_hist,
                                                      unsigned int* __restrict__ part,
                                                      int E, int NB) {
    __shared__ int cur[NB_MAX];
    int tid = threadIdx.x;
    int blk = blockIdx.x;
    for (int i = tid; i < NB; i += 256) cur[i] = blk_hist[(size_t)blk * NB + i];
    __syncthreads();
    int cb = blk * CHUNK;
    #pragma unroll
    for (int k = 0; k < CHUNK / 1024; k++) {
        int e = cb + (k * 256 + tid) * 4;
        if (e + 3 < E) {
            int4 d4 = *(const int4*)&dst[e];
            int4 s4 = *(const int4*)&src[e];
            int p0 = atomicAdd(&cur[d4.x >> BSHIFT], 1);
            part[p0] = ((unsigned int)(d4.x & (BNODES - 1)) << 24) | (unsigned int)s4.x;
            int p1 = atomicAdd(&cur[d4.y >> BSHIFT], 1);
            part[p1] = ((unsigned int)(d4.y & (BNODES - 1)) << 24) | (unsigned int)s4.y;
            int p2 = atomicAdd(&cur[d4.z >> BSHIFT], 1);
            part[p2] = ((unsigned int)(d4.z & (BNODES - 1)) << 24) | (unsigned int)s4.z;
            int p3 = atomicAdd(&cur[d4.w >> BSHIFT], 1);
            part[p3] = ((unsigned int)(d4.w & (BNODES - 1)) << 24) | (unsigned int)s4.w;
        } else {
            for (int t = 0; t < 4; t++)
                if (e + t < E) {
                    int d = dst[e + t];
                    int pos = atomicAdd(&cur[d >> BSHIFT], 1);
                    part[pos] = ((unsigned int)(d & (BNODES - 1)) << 24) | (unsigned int)src[e + t];
                }
        }
    }
}

// ---------- pass 4: per-bucket counting sort -> csr_src, row_ptr, dis ----------
__global__ __launch_bounds__(256) void csr_build(const unsigned int* __restrict__ part,
                                                 const int* __restrict__ bucket_base,
                                                 int* __restrict__ csr_src,
                                                 int* __restrict__ row_ptr,
                                                 float* __restrict__ dis,
                                                 int N) {
    __shared__ unsigned int eL[CAP];
    __shared__ unsigned int outL[CAP];
    __shared__ int cnt[BNODES];
    __shared__ int sc[BNODES];
    __shared__ int cur[BNODES];
    int tid = threadIdx.x;
    int b = blockIdx.x;
    int eB = bucket_base[b];
    int eN = bucket_base[b + 1] - eB;
    if (eN > CAP) eN = CAP;

    cnt[tid] = 0;
    __syncthreads();
    for (int i = tid; i < eN; i += 256) {
        unsigned int v = part[eB + i];
        eL[i] = v;
        atomicAdd(&cnt[v >> 24], 1);
    }
    __syncthreads();
    int myc = cnt[tid];
    sc[tid] = myc;
    __syncthreads();
    for (int off = 1; off < 256; off <<= 1) {
        int t = (tid >= off) ? sc[tid - off] : 0;
        __syncthreads();
        sc[tid] += t;
        __syncthreads();
    }
    int excl = sc[tid] - myc;
    cur[tid] = excl;
    int gnode = b * BNODES + tid;
    if (gnode < N) {
        row_ptr[gnode] = eB + excl;
        float d = (float)myc;
        dis[gnode] = d > 0.0f ? rsqrtf(fmaxf(d, 1.0f)) : 0.0f;
    }
    __syncthreads();
    for (int i = tid; i < eN; i += 256) {
        unsigned int v = eL[i];
        int pos = atomicAdd(&cur[v >> 24], 1);
        outL[pos] = v & 0xFFFFFFu;
    }
    __syncthreads();
    for (int i = tid; i < eN; i += 256)
        csr_src[eB + i] = (int)outL[i];
}

// ---------- gemm1 via MFMA bf16: 64 rows/block; also emits zeroed sentinel row N ----------
__global__ __launch_bounds__(256) void gemm1_kernel(
        const float* __restrict__ x, const unsigned short* __restrict__ w1t,
        const float* __restrict__ dis, unsigned short* __restrict__ h1b, int N) {
    __shared__ unsigned short xs[64][136];
    __shared__ unsigned short wsb[64][136];
    __shared__ float diss[64];
    int tid = threadIdx.x;
    int w = tid >> 6;
    int lane = tid & 63;
    int row0 = blockIdx.x * 64;

    #pragma unroll
    for (int it = 0; it < 8; it++) {
        int f = it * 256 + tid;
        int r = f >> 5, c = f & 31;
        float4 v = make_float4(0.f, 0.f, 0.f, 0.f);
        if (row0 + r < N) v = ((const float4*)x)[(size_t)(row0 + r) * 32 + c];
        unsigned int p0 = (unsigned int)f2bf(v.x) | ((unsigned int)f2bf(v.y) << 16);
        unsigned int p1 = (unsigned int)f2bf(v.z) | ((unsigned int)f2bf(v.w) << 16);
        *(uint2*)&xs[r][c * 4] = make_uint2(p0, p1);
    }
    #pragma unroll
    for (int it = 0; it < 4; it++) {
        int f = it * 256 + tid;
        int r = f >> 4, c = f & 15;
        *(uint4*)&wsb[r][c * 8] = ((const uint4*)w1t)[f];
    }
    if (tid < 64) diss[tid] = (row0 + tid < N) ? dis[row0 + tid] : 0.f;
    __syncthreads();

    int q = lane >> 4;
    int l15 = lane & 15;
    f32x4 acc[4] = {{0,0,0,0},{0,0,0,0},{0,0,0,0},{0,0,0,0}};
    bf16x8 a[4];
    #pragma unroll
    for (int kk = 0; kk < 4; kk++)
        a[kk] = *(const bf16x8*)&xs[w * 16 + l15][kk * 32 + q * 8];
    #pragma unroll
    for (int kk = 0; kk < 4; kk++) {
        #pragma unroll
        for (int ct = 0; ct < 4; ct++) {
            bf16x8 b = *(const bf16x8*)&wsb[ct * 16 + l15][kk * 32 + q * 8];
            acc[ct] = __builtin_amdgcn_mfma_f32_16x16x32_bf16(a[kk], b, acc[ct], 0, 0, 0);
        }
    }
    __syncthreads();
    #pragma unroll
    for (int ct = 0; ct < 4; ct++) {
        #pragma unroll
        for (int r = 0; r < 4; r++) {
            int m = w * 16 + q * 4 + r;
            xs[m][ct * 16 + l15] = f2bf(acc[ct][r] * diss[m]);
        }
    }
    __syncthreads();
    #pragma unroll
    for (int it = 0; it < 2; it++) {
        int f = it * 256 + tid;
        int r = f >> 3, c = f & 7;
        if (row0 + r < N + 1)   // row N written as zeros (diss=0) -> gather sentinel
            ((uint4*)&h1b[(size_t)(row0 + r) * HID])[c] = *(const uint4*)&xs[r][c * 8];
    }
}

// ---------- fused layer-1 agg + ReLU + W2 GEMM ----------
// 1 node/wave, 8 slots x 8 dim-lanes; flat batch of 32 edges:
// 4 independent index loads + sentinel cndmask + 4 independent 16B gathers.
__global__ __launch_bounds__(256) void agg1_fused(
        const int* __restrict__ row_ptr, const int* __restrict__ csr_src,
        const unsigned short* __restrict__ h1b, const float* __restrict__ dis,
        const float* __restrict__ b1, const float* __restrict__ W2,
        unsigned short* __restrict__ h2b, int N) {
    __shared__ float W2t[NCLS][HID + 4];   // transposed, padded row stride 68
    __shared__ float ts[4][HID];
    int tid = threadIdx.x;
    int w = tid >> 6;
    int lane = tid & 63;
    int sub = lane & 7;        // dims sub*8 .. sub*8+7 (16B)
    int slot = lane >> 3;      // edge slot 0..7
    int n = blockIdx.x * 4 + w;
    int nc = (n < N) ? n : 0;  // clamp so inactive waves still load safely

    // issue row_ptr + index loads BEFORE LDS staging (latency hides under it)
    int beg = row_ptr[nc];
    int end = row_ptr[nc + 1];
    int i0 = beg + slot;
    int s0 = csr_src[i0];           // csr_src has +64 slack; garbage masked below
    int s1 = csr_src[i0 + 8];
    int s2 = csr_src[i0 + 16];
    int s3 = csr_src[i0 + 24];

    for (int i = tid; i < HID * NCLS; i += 256) W2t[i & 15][i >> 4] = W2[i];
    __syncthreads();
    if (n >= N) return;        // wave-uniform exit (after the only __syncthreads)
    float dn = dis[n];

    // sentinel-replace invalid slots: row N of h1b is zeros (and L1-hot)
    s0 = (i0      < end) ? s0 : N;
    s1 = (i0 + 8  < end) ? s1 : N;
    s2 = (i0 + 16 < end) ? s2 : N;
    s3 = (i0 + 24 < end) ? s3 : N;
    const unsigned short* hp = h1b + sub * 8;
    uint4 v0 = *(const uint4*)(hp + (unsigned)s0 * HID);
    uint4 v1 = *(const uint4*)(hp + (unsigned)s1 * HID);
    uint4 v2 = *(const uint4*)(hp + (unsigned)s2 * HID);
    uint4 v3 = *(const uint4*)(hp + (unsigned)s3 * HID);
    f32x2 a0 = bfpair(v0.x) + bfpair(v1.x);
    f32x2 a1 = bfpair(v0.y) + bfpair(v1.y);
    f32x2 a2 = bfpair(v0.z) + bfpair(v1.z);
    f32x2 a3 = bfpair(v0.w) + bfpair(v1.w);
    a0 += bfpair(v2.x) + bfpair(v3.x);
    a1 += bfpair(v2.y) + bfpair(v3.y);
    a2 += bfpair(v2.z) + bfpair(v3.z);
    a3 += bfpair(v2.w) + bfpair(v3.w);
    // residual for rare deg > 32 rows (wave-uniform trip decision per slot)
    for (int i = beg + 32 + slot; i < end; i += 8) {
        int s = csr_src[i];
        uint4 v = *(const uint4*)(hp + (unsigned)s * HID);
        a0 += bfpair(v.x);
        a1 += bfpair(v.y);
        a2 += bfpair(v.z);
        a3 += bfpair(v.w);
    }
    // reduce across 8 slots (lane bits 3,4,5)
    #pragma unroll
    for (int m = 8; m <= 32; m <<= 1) {
        a0.x += __shfl_xor(a0.x, m, 64); a0.y += __shfl_xor(a0.y, m, 64);
        a1.x += __shfl_xor(a1.x, m, 64); a1.y += __shfl_xor(a1.y, m, 64);
        a2.x += __shfl_xor(a2.x, m, 64); a2.y += __shfl_xor(a2.y, m, 64);
        a3.x += __shfl_xor(a3.x, m, 64); a3.y += __shfl_xor(a3.y, m, 64);
    }
    if (slot == 0) {
        float4 bl = ((const float4*)b1)[sub * 2];
        float4 bh = ((const float4*)b1)[sub * 2 + 1];
        float4 r0, r1;
        r0.x = fmaxf(fmaf(dn, a0.x, bl.x), 0.f);
        r0.y = fmaxf(fmaf(dn, a0.y, bl.y), 0.f);
        r0.z = fmaxf(fmaf(dn, a1.x, bl.z), 0.f);
        r0.w = fmaxf(fmaf(dn, a1.y, bl.w), 0.f);
        r1.x = fmaxf(fmaf(dn, a2.x, bh.x), 0.f);
        r1.y = fmaxf(fmaf(dn, a2.y, bh.y), 0.f);
        r1.z = fmaxf(fmaf(dn, a3.x, bh.z), 0.f);
        r1.w = fmaxf(fmaf(dn, a3.y, bh.w), 0.f);
        *(float4*)&ts[w][sub * 8] = r0;
        *(float4*)&ts[w][sub * 8 + 4] = r1;
    }
    // wave-local LDS round-trip (same wave writes+reads; compiler inserts lgkmcnt)
    int q = lane >> 4, c = lane & 15;
    const float* tp = &ts[w][q * 16];
    const float* wp = &W2t[c][q * 16];
    float4 t0 = *(const float4*)tp,       t1 = *(const float4*)(tp + 4);
    float4 t2 = *(const float4*)(tp + 8), t3 = *(const float4*)(tp + 12);
    float4 u0 = *(const float4*)wp,       u1 = *(const float4*)(wp + 4);
    float4 u2 = *(const float4*)(wp + 8), u3 = *(const float4*)(wp + 12);
    float p = t0.x * u0.x + t0.y * u0.y + t0.z * u0.z + t0.w * u0.w
            + t1.x * u1.x + t1.y * u1.y + t1.z * u1.z + t1.w * u1.w
            + t2.x * u2.x + t2.y * u2.y + t2.z * u2.z + t2.w * u2.w
            + t3.x * u3.x + t3.y * u3.y + t3.z * u3.z + t3.w * u3.w;
    p += __shfl_xor(p, 16, 64);
    p += __shfl_xor(p, 32, 64);
    if (lane < 16) h2b[(unsigned)n * NCLS + c] = f2bf(p * dn);
}

// ---------- fused layer-2 agg + epilogue ----------
// 4 nodes/wave, 8 slots x 2 dim-lanes; same flat-batch-32 + sentinel scheme
__global__ __launch_bounds__(256) void agg2_fused(
        const int* __restrict__ row_ptr, const int* __restrict__ csr_src,
        const unsigned short* __restrict__ h2b, const float* __restrict__ dis,
        const float* __restrict__ b2, float* __restrict__ out, int N) {
    int t = blockIdx.x * 256 + threadIdx.x;
    int lane = t & 63;
    int grp = lane >> 4;         // node within wave
    int slot = (lane >> 1) & 7;  // edge slot
    int sub = lane & 1;          // dims sub*8 .. sub*8+7
    int n = (t >> 6) * 4 + grp;
    if (n >= N) return;          // uniform within each 16-lane group
    int beg = row_ptr[n];
    int end = row_ptr[n + 1];
    int i0 = beg + slot;
    int s0 = csr_src[i0];
    int s1 = csr_src[i0 + 8];
    int s2 = csr_src[i0 + 16];
    int s3 = csr_src[i0 + 24];
    s0 = (i0      < end) ? s0 : N;   // row N of h2b is zeros
    s1 = (i0 + 8  < end) ? s1 : N;
    s2 = (i0 + 16 < end) ? s2 : N;
    s3 = (i0 + 24 < end) ? s3 : N;
    const unsigned short* hp = h2b + sub * 8;
    uint4 v0 = *(const uint4*)(hp + (unsigned)s0 * NCLS);
    uint4 v1 = *(const uint4*)(hp + (unsigned)s1 * NCLS);
    uint4 v2 = *(const uint4*)(hp + (unsigned)s2 * NCLS);
    uint4 v3 = *(const uint4*)(hp + (unsigned)s3 * NCLS);
    f32x2 a0 = bfpair(v0.x) + bfpair(v1.x);
    f32x2 a1 = bfpair(v0.y) + bfpair(v1.y);
    f32x2 a2 = bfpair(v0.z) + bfpair(v1.z);
    f32x2 a3 = bfpair(v0.w) + bfpair(v1.w);
    a0 += bfpair(v2.x) + bfpair(v3.x);
    a1 += bfpair(v2.y) + bfpair(v3.y);
    a2 += bfpair(v2.z) + bfpair(v3.z);
    a3 += bfpair(v2.w) + bfpair(v3.w);
    for (int i = beg + 32 + slot; i < end; i += 8) {
        int s = csr_src[i];
        uint4 v = *(const uint4*)(hp + (unsigned)s * NCLS);
        a0 += bfpair(v.x);
        a1 += bfpair(v.y);
        a2 += bfpair(v.z);
        a3 += bfpair(v.w);
    }
    // reduce across 8 slots (lane bits 1,2,3 — stays inside the 16-lane group)
    #pragma unroll
    for (int m = 2; m <= 8; m <<= 1) {
        a0.x += __shfl_xor(a0.x, m, 64); a0.y += __shfl_xor(a0.y, m, 64);
        a1.x += __shfl_xor(a1.x, m, 64); a1.y += __shfl_xor(a1.y, m, 64);
        a2.x += __shfl_xor(a2.x, m, 64); a2.y += __shfl_xor(a2.y, m, 64);
        a3.x += __shfl_xor(a3.x, m, 64); a3.y += __shfl_xor(a3.y, m, 64);
    }
    if (slot == 0) {
        float dn = dis[n];
        float4 bl = ((const float4*)b2)[sub * 2];
        float4 bh = ((const float4*)b2)[sub * 2 + 1];
        float4 o0, o1;
        o0.x = fmaf(dn, a0.x, bl.x); o0.y = fmaf(dn, a0.y, bl.y);
        o0.z = fmaf(dn, a1.x, bl.z); o0.w = fmaf(dn, a1.y, bl.w);
        o1.x = fmaf(dn, a2.x, bh.x); o1.y = fmaf(dn, a2.y, bh.y);
        o1.z = fmaf(dn, a3.x, bh.z); o1.w = fmaf(dn, a3.y, bh.w);
        float* op = out + (unsigned)n * NCLS + sub * 8;
        *(float4*)op = o0;
        *(float4*)(op + 4) = o1;
    }
}

extern "C" void kernel_launch(void* const* d_in, const int* in_sizes, int n_in,
                              void* d_out, int out_size, void* d_ws, size_t ws_size,
                              hipStream_t stream) {
    const float* x   = (const float*)d_in[0];
    const int*   src = (const int*)  d_in[1];
    const int*   dst = (const int*)  d_in[2];
    const float* W1  = (const float*)d_in[3];
    const float* b1  = (const float*)d_in[4];
    const float* W2  = (const float*)d_in[5];
    const float* b2  = (const float*)d_in[6];
    float* out = (float*)d_out;
    int E = in_sizes[1];
    int N = in_sizes[0] / F_IN;
    int NB = (N + BNODES - 1) >> BSHIFT;
    int nchunks = (E + CHUNK - 1) / CHUNK;   // 208 for E=1.7M (col_scan requires <=256)

    char* ws = (char*)d_ws;
    size_t off = 0;
    auto alloc = [&](size_t bytes) { size_t o = off; off = (off + bytes + 255) & ~(size_t)255; return (void*)(ws + o); };
    int*   bucket_count  = (int*)  alloc((size_t)NB * 4);
    int*   bucket_base   = (int*)  alloc((size_t)(NB + 1) * 4);
    int*   blk_hist      = (int*)  alloc((size_t)nchunks * NB * 4);
    int*   row_ptr       = (int*)  alloc((size_t)(N + 1) * 4);
    int*   csr_src       = (int*)  alloc((size_t)(E + 64) * 4);   // +64 slack for batch over-read
    float* dis           = (float*)alloc((size_t)N * 4);
    unsigned short* w1t  = (unsigned short*)alloc((size_t)F_IN * HID * 2);
    unsigned short* h1b  = (unsigned short*)alloc((size_t)(N + 1) * HID * 2);  // +1 sentinel row
    unsigned short* h2b  = (unsigned short*)alloc((size_t)(N + 1) * NCLS * 2); // +1 sentinel row
    // part[] aliases h1b: dead before gemm1 writes h1b (E*4 = 6.8MB <= (N+1)*HID*2 = 12.8MB)
    unsigned int* part   = (unsigned int*)h1b;

    hist_w1t_kernel<<<nchunks + 1, 256, 0, stream>>>(dst, blk_hist, W1, w1t, h2b, E, N, NB, nchunks);
    col_reduce     <<<NB, 256, 0, stream>>>(blk_hist, bucket_count, NB, nchunks);
    scan_small     <<<1, 512, 0, stream>>>(bucket_count, bucket_base, row_ptr, NB, N, E);
    col_scan       <<<NB, 256, 0, stream>>>(blk_hist, bucket_base, NB, nchunks);
    scatter_kernel <<<nchunks, 256, 0, stream>>>(src, dst, blk_hist, part, E, NB);
    csr_build      <<<NB, 256, 0, stream>>>(part, bucket_base, csr_src, row_ptr, dis, N);
    gemm1_kernel   <<<(N + 64) / 64, 256, 0, stream>>>(x, w1t, dis, h1b, N);  // +1 covers row N
    agg1_fused     <<<(N + 3) / 4, 256, 0, stream>>>(row_ptr, csr_src, h1b, dis, b1, W2, h2b, N);
    agg2_fused     <<<(N + 15) / 16, 256, 0, stream>>>(row_ptr, csr_src, h2b, dis, b2, out, N);
}

// Round 5
// 209.975 us; speedup vs baseline: 1.9389x; 1.0473x over previous
//
#include <hip/hip_runtime.h>

#define F_IN 128
#define HID  64
#define NCLS 16

#define BSHIFT 8            // 256 nodes per bucket
#define BNODES 256
#define NB_MAX 512          // max buckets (N<=128k)
#define CHUNK  8192         // edges per partition block (nchunks must be <=256 for col_scan)
#define CAP    8192         // max edges per bucket in LDS (mean 4352, 50+ sigma margin)

typedef __attribute__((ext_vector_type(2))) float f32x2;
typedef __attribute__((ext_vector_type(8))) short bf16x8;
typedef __attribute__((ext_vector_type(4))) float f32x4;

// round-to-nearest-even fp32 -> bf16
__device__ __forceinline__ unsigned short f2bf(float f) {
    unsigned int u = __float_as_uint(f);
    u += 0x7FFFu + ((u >> 16) & 1u);
    return (unsigned short)(u >> 16);
}
// one dword = 2 packed bf16 -> f32x2 (2 VALU unpack + packed add)
__device__ __forceinline__ f32x2 bfpair(unsigned int u) {
    f32x2 r;
    r.x = __uint_as_float(u << 16);
    r.y = __uint_as_float(u & 0xFFFF0000u);
    return r;
}

// ---------- pass 1: per-block bucket histogram (non-atomic global) + fused w1t ----------
__global__ __launch_bounds__(256) void hist_w1t_kernel(const int* __restrict__ dst,
                                                       int* __restrict__ blk_hist,
                                                       const float* __restrict__ W1,
                                                       unsigned short* __restrict__ w1t,
                                                       unsigned short* __restrict__ h2b,
                                                       int E, int N, int NB, int nchunks) {
    int blk = blockIdx.x;
    int tid = threadIdx.x;
    if (blk == nchunks) {           // fused W1 -> bf16 transpose block
        for (int i = tid; i < F_IN * HID; i += 256) {
            int k = i >> 6, n = i & 63;
            w1t[n * F_IN + k] = f2bf(W1[i]);
        }
        if (tid < NCLS) h2b[(size_t)N * NCLS + tid] = 0;   // zero sentinel row for agg2
        return;
    }
    __shared__ int hist[NB_MAX];
    for (int i = tid; i < NB; i += 256) hist[i] = 0;
    __syncthreads();
    int cb = blk * CHUNK;
    #pragma unroll
    for (int k = 0; k < CHUNK / 1024; k++) {
        int e = cb + (k * 256 + tid) * 4;
        if (e + 3 < E) {
            int4 d4 = *(const int4*)&dst[e];
            atomicAdd(&hist[d4.x >> BSHIFT], 1);
            atomicAdd(&hist[d4.y >> BSHIFT], 1);
            atomicAdd(&hist[d4.z >> BSHIFT], 1);
            atomicAdd(&hist[d4.w >> BSHIFT], 1);
        } else {
            for (int t = 0; t < 4; t++)
                if (e + t < E) atomicAdd(&hist[dst[e + t] >> BSHIFT], 1);
        }
    }
    __syncthreads();
    for (int i = tid; i < NB; i += 256) blk_hist[(size_t)blk * NB + i] = hist[i];
}

// ---------- pass 2: fused column-reduce + scan (single block, 512 threads) ----------
__global__ __launch_bounds__(512) void bucket_scan(const int* __restrict__ blk_hist,
                                                   int* __restrict__ bucket_base,
                                                   int* __restrict__ row_ptr,
                                                   int NB, int N, int E, int nchunks) {
    __shared__ int s[512];
    int tid = threadIdx.x;
    int v = 0;
    if (tid < NB) {
        #pragma unroll 4
        for (int j = 0; j < nchunks; j++) v += blk_hist[(size_t)j * NB + tid];
    }
    s[tid] = v;
    __syncthreads();
    for (int off = 1; off < 512; off <<= 1) {
        int t = (tid >= off) ? s[tid - off] : 0;
        __syncthreads();
        s[tid] += t;
        __syncthreads();
    }
    if (tid < NB) bucket_base[tid] = s[tid] - v;
    if (tid == 0) { bucket_base[NB] = E; row_ptr[N] = E; }
}

// ---------- pass 2c: per-bucket parallel column scan -> absolute per-chunk bases ----------
__global__ __launch_bounds__(256) void col_scan(int* __restrict__ blk_hist,
                                                const int* __restrict__ bucket_base,
                                                int NB, int nchunks) {
    __shared__ int s[256];
    int b = blockIdx.x;
    int tid = threadIdx.x;
    int v = (tid < nchunks) ? blk_hist[(size_t)tid * NB + b] : 0;
    s[tid] = v;
    __syncthreads();
    for (int off = 1; off < 256; off <<= 1) {
        int t = (tid >= off) ? s[tid - off] : 0;
        __syncthreads();
        s[tid] += t;
        __syncthreads();
    }
    if (tid < nchunks) blk_hist[(size_t)tid * NB + b] = s[tid] - v + bucket_base[b];
}

// ---------- pass 3: single-pass partition (LDS cursors, coalesced per-bucket runs) ----------
__global__ __launch_bounds__(256) void scatter_kernel(const int* __restrict__ src,
                                                      const int* __restrict__ dst,
                                                      const int* __restrict__ blk_hist,
                                                      unsigned int* __restrict__ part,
                                                      int E, int NB) {
    __shared__ int cur[NB_MAX];
    int tid = threadIdx.x;
    int blk = blockIdx.x;
    for (int i = tid; i < NB; i += 256) cur[i] = blk_hist[(size_t)blk * NB + i];
    __syncthreads();
    int cb = blk * CHUNK;
    #pragma unroll
    for (int k = 0; k < CHUNK / 1024; k++) {
        int e = cb + (k * 256 + tid) * 4;
        if (e + 3 < E) {
            int4 d4 = *(const int4*)&dst[e];
            int4 s4 = *(const int4*)&src[e];
            int p0 = atomicAdd(&cur[d4.x >> BSHIFT], 1);
            part[p0] = ((unsigned int)(d4.x & (BNODES - 1)) << 24) | (unsigned int)s4.x;
            int p1 = atomicAdd(&cur[d4.y >> BSHIFT], 1);
            part[p1] = ((unsigned int)(d4.y & (BNODES - 1)) << 24) | (unsigned int)s4.y;
            int p2 = atomicAdd(&cur[d4.z >> BSHIFT], 1);
            part[p2] = ((unsigned int)(d4.z & (BNODES - 1)) << 24) | (unsigned int)s4.z;
            int p3 = atomicAdd(&cur[d4.w >> BSHIFT], 1);
            part[p3] = ((unsigned int)(d4.w & (BNODES - 1)) << 24) | (unsigned int)s4.w;
        } else {
            for (int t = 0; t < 4; t++)
                if (e + t < E) {
                    int d = dst[e + t];
                    int pos = atomicAdd(&cur[d >> BSHIFT], 1);
                    part[pos] = ((unsigned int)(d & (BNODES - 1)) << 24) | (unsigned int)src[e + t];
                }
        }
    }
}

// ---------- pass 4: per-bucket counting sort -> csr_src, row_ptr, dis ----------
__global__ __launch_bounds__(256) void csr_build(const unsigned int* __restrict__ part,
                                                 const int* __restrict__ bucket_base,
                                                 int* __restrict__ csr_src,
                                                 int* __restrict__ row_ptr,
                                                 float* __restrict__ dis,
                                                 int N) {
    __shared__ unsigned int eL[CAP];
    __shared__ unsigned int outL[CAP];
    __shared__ int cnt[BNODES];
    __shared__ int sc[BNODES];
    __shared__ int cur[BNODES];
    int tid = threadIdx.x;
    int b = blockIdx.x;
    int eB = bucket_base[b];
    int eN = bucket_base[b + 1] - eB;
    if (eN > CAP) eN = CAP;

    cnt[tid] = 0;
    __syncthreads();
    for (int i = tid; i < eN; i += 256) {
        unsigned int v = part[eB + i];
        eL[i] = v;
        atomicAdd(&cnt[v >> 24], 1);
    }
    __syncthreads();
    int myc = cnt[tid];
    sc[tid] = myc;
    __syncthreads();
    for (int off = 1; off < 256; off <<= 1) {
        int t = (tid >= off) ? sc[tid - off] : 0;
        __syncthreads();
        sc[tid] += t;
        __syncthreads();
    }
    int excl = sc[tid] - myc;
    cur[tid] = excl;
    int gnode = b * BNODES + tid;
    if (gnode < N) {
        row_ptr[gnode] = eB + excl;
        float d = (float)myc;
        dis[gnode] = d > 0.0f ? rsqrtf(fmaxf(d, 1.0f)) : 0.0f;
    }
    __syncthreads();
    for (int i = tid; i < eN; i += 256) {
        unsigned int v = eL[i];
        int pos = atomicAdd(&cur[v >> 24], 1);
        outL[pos] = v & 0xFFFFFFu;
    }
    __syncthreads();
    for (int i = tid; i < eN; i += 256)
        csr_src[eB + i] = (int)outL[i];
}

// ---------- gemm1 via MFMA bf16: 64 rows/block; also emits zeroed sentinel row N ----------
__global__ __launch_bounds__(256) void gemm1_kernel(
        const float* __restrict__ x, const unsigned short* __restrict__ w1t,
        const float* __restrict__ dis, unsigned short* __restrict__ h1b, int N) {
    __shared__ unsigned short xs[64][136];
    __shared__ unsigned short wsb[64][136];
    __shared__ float diss[64];
    int tid = threadIdx.x;
    int w = tid >> 6;
    int lane = tid & 63;
    int row0 = blockIdx.x * 64;

    #pragma unroll
    for (int it = 0; it < 8; it++) {
        int f = it * 256 + tid;
        int r = f >> 5, c = f & 31;
        float4 v = make_float4(0.f, 0.f, 0.f, 0.f);
        if (row0 + r < N) v = ((const float4*)x)[(size_t)(row0 + r) * 32 + c];
        unsigned int p0 = (unsigned int)f2bf(v.x) | ((unsigned int)f2bf(v.y) << 16);
        unsigned int p1 = (unsigned int)f2bf(v.z) | ((unsigned int)f2bf(v.w) << 16);
        *(uint2*)&xs[r][c * 4] = make_uint2(p0, p1);
    }
    #pragma unroll
    for (int it = 0; it < 4; it++) {
        int f = it * 256 + tid;
        int r = f >> 4, c = f & 15;
        *(uint4*)&wsb[r][c * 8] = ((const uint4*)w1t)[f];
    }
    if (tid < 64) diss[tid] = (row0 + tid < N) ? dis[row0 + tid] : 0.f;
    __syncthreads();

    int q = lane >> 4;
    int l15 = lane & 15;
    f32x4 acc[4] = {{0,0,0,0},{0,0,0,0},{0,0,0,0},{0,0,0,0}};
    bf16x8 a[4];
    #pragma unroll
    for (int kk = 0; kk < 4; kk++)
        a[kk] = *(const bf16x8*)&xs[w * 16 + l15][kk * 32 + q * 8];
    #pragma unroll
    for (int kk = 0; kk < 4; kk++) {
        #pragma unroll
        for (int ct = 0; ct < 4; ct++) {
            bf16x8 b = *(const bf16x8*)&wsb[ct * 16 + l15][kk * 32 + q * 8];
            acc[ct] = __builtin_amdgcn_mfma_f32_16x16x32_bf16(a[kk], b, acc[ct], 0, 0, 0);
        }
    }
    __syncthreads();
    #pragma unroll
    for (int ct = 0; ct < 4; ct++) {
        #pragma unroll
        for (int r = 0; r < 4; r++) {
            int m = w * 16 + q * 4 + r;
            xs[m][ct * 16 + l15] = f2bf(acc[ct][r] * diss[m]);
        }
    }
    __syncthreads();
    #pragma unroll
    for (int it = 0; it < 2; it++) {
        int f = it * 256 + tid;
        int r = f >> 3, c = f & 7;
        if (row0 + r < N + 1)   // row N written as zeros (diss=0) -> gather sentinel
            ((uint4*)&h1b[(size_t)(row0 + r) * HID])[c] = *(const uint4*)&xs[r][c * 8];
    }
}

// ---------- fused layer-1 agg + ReLU + W2 GEMM ----------
// 2 nodes/wave (half-wave each: 4 slots x 8 dim-lanes), flat batch of 32 edges:
// 8 independent index loads + sentinel cndmask + 8 independent 16B gathers per lane.
__global__ __launch_bounds__(256) void agg1_fused(
        const int* __restrict__ row_ptr, const int* __restrict__ csr_src,
        const unsigned short* __restrict__ h1b, const float* __restrict__ dis,
        const float* __restrict__ b1, const float* __restrict__ W2,
        unsigned short* __restrict__ h2b, int N) {
    __shared__ float W2t[NCLS][HID + 4];   // transposed, padded row stride 68
    __shared__ float ts[8][HID];
    int tid = threadIdx.x;
    int w = tid >> 6;
    int lane = tid & 63;
    int half = lane >> 5;      // node within wave
    int hl = lane & 31;        // lane within half
    int sub = hl & 7;          // dims sub*8 .. sub*8+7 (16B)
    int slot = hl >> 3;        // edge slot 0..3
    int n = blockIdx.x * 8 + w * 2 + half;
    int nc = (n < N) ? n : 0;  // clamp so tail lanes still load safely

    // issue row_ptr + index + dis loads BEFORE LDS staging (latency hides under it)
    int beg = row_ptr[nc];
    int end = row_ptr[nc + 1];
    float dn = dis[nc];
    int i0 = beg + slot;
    int s0 = csr_src[i0];           // csr_src has +64 slack; garbage masked below
    int s1 = csr_src[i0 + 4];
    int s2 = csr_src[i0 + 8];
    int s3 = csr_src[i0 + 12];
    int s4 = csr_src[i0 + 16];
    int s5 = csr_src[i0 + 20];
    int s6 = csr_src[i0 + 24];
    int s7 = csr_src[i0 + 28];

    for (int i = tid; i < HID * NCLS; i += 256) W2t[i & 15][i >> 4] = W2[i];
    __syncthreads();
    if (n >= N) return;        // after the only __syncthreads (no barrier below)

    // sentinel-replace invalid slots: row N of h1b is zeros (and cache-hot)
    s0 = (i0      < end) ? s0 : N;
    s1 = (i0 + 4  < end) ? s1 : N;
    s2 = (i0 + 8  < end) ? s2 : N;
    s3 = (i0 + 12 < end) ? s3 : N;
    s4 = (i0 + 16 < end) ? s4 : N;
    s5 = (i0 + 20 < end) ? s5 : N;
    s6 = (i0 + 24 < end) ? s6 : N;
    s7 = (i0 + 28 < end) ? s7 : N;
    const unsigned short* hp = h1b + sub * 8;
    uint4 v0 = *(const uint4*)(hp + (unsigned)s0 * HID);
    uint4 v1 = *(const uint4*)(hp + (unsigned)s1 * HID);
    uint4 v2 = *(const uint4*)(hp + (unsigned)s2 * HID);
    uint4 v3 = *(const uint4*)(hp + (unsigned)s3 * HID);
    uint4 v4 = *(const uint4*)(hp + (unsigned)s4 * HID);
    uint4 v5 = *(const uint4*)(hp + (unsigned)s5 * HID);
    uint4 v6 = *(const uint4*)(hp + (unsigned)s6 * HID);
    uint4 v7 = *(const uint4*)(hp + (unsigned)s7 * HID);
    f32x2 a0 = (bfpair(v0.x) + bfpair(v1.x)) + (bfpair(v2.x) + bfpair(v3.x));
    f32x2 a1 = (bfpair(v0.y) + bfpair(v1.y)) + (bfpair(v2.y) + bfpair(v3.y));
    f32x2 a2 = (bfpair(v0.z) + bfpair(v1.z)) + (bfpair(v2.z) + bfpair(v3.z));
    f32x2 a3 = (bfpair(v0.w) + bfpair(v1.w)) + (bfpair(v2.w) + bfpair(v3.w));
    a0 += (bfpair(v4.x) + bfpair(v5.x)) + (bfpair(v6.x) + bfpair(v7.x));
    a1 += (bfpair(v4.y) + bfpair(v5.y)) + (bfpair(v6.y) + bfpair(v7.y));
    a2 += (bfpair(v4.z) + bfpair(v5.z)) + (bfpair(v6.z) + bfpair(v7.z));
    a3 += (bfpair(v4.w) + bfpair(v5.w)) + (bfpair(v6.w) + bfpair(v7.w));
    // residual for rare deg > 32 rows
    for (int i = beg + 32 + slot; i < end; i += 4) {
        int s = csr_src[i];
        uint4 v = *(const uint4*)(hp + (unsigned)s * HID);
        a0 += bfpair(v.x);
        a1 += bfpair(v.y);
        a2 += bfpair(v.z);
        a3 += bfpair(v.w);
    }
    // reduce across the 4 slots (lane bits 3,4 — stays within the half)
    #pragma unroll
    for (int m = 8; m <= 16; m <<= 1) {
        a0.x += __shfl_xor(a0.x, m, 64); a0.y += __shfl_xor(a0.y, m, 64);
        a1.x += __shfl_xor(a1.x, m, 64); a1.y += __shfl_xor(a1.y, m, 64);
        a2.x += __shfl_xor(a2.x, m, 64); a2.y += __shfl_xor(a2.y, m, 64);
        a3.x += __shfl_xor(a3.x, m, 64); a3.y += __shfl_xor(a3.y, m, 64);
    }
    if (slot == 0) {
        float4 bl = ((const float4*)b1)[sub * 2];
        float4 bh = ((const float4*)b1)[sub * 2 + 1];
        float4 r0, r1;
        r0.x = fmaxf(fmaf(dn, a0.x, bl.x), 0.f);
        r0.y = fmaxf(fmaf(dn, a0.y, bl.y), 0.f);
        r0.z = fmaxf(fmaf(dn, a1.x, bl.z), 0.f);
        r0.w = fmaxf(fmaf(dn, a1.y, bl.w), 0.f);
        r1.x = fmaxf(fmaf(dn, a2.x, bh.x), 0.f);
        r1.y = fmaxf(fmaf(dn, a2.y, bh.y), 0.f);
        r1.z = fmaxf(fmaf(dn, a3.x, bh.z), 0.f);
        r1.w = fmaxf(fmaf(dn, a3.y, bh.w), 0.f);
        *(float4*)&ts[w * 2 + half][sub * 8] = r0;
        *(float4*)&ts[w * 2 + half][sub * 8 + 4] = r1;
    }
    // wave-local LDS round-trip (same wave writes+reads; compiler inserts lgkmcnt)
    int q = hl >> 4, c = hl & 15;       // q: K-half 0/1, c: output class
    const float* tp = &ts[w * 2 + half][q * 32];
    const float* wp = &W2t[c][q * 32];
    float4 t0 = *(const float4*)tp,        t1 = *(const float4*)(tp + 4);
    float4 t2 = *(const float4*)(tp + 8),  t3 = *(const float4*)(tp + 12);
    float4 t4 = *(const float4*)(tp + 16), t5 = *(const float4*)(tp + 20);
    float4 t6 = *(const float4*)(tp + 24), t7 = *(const float4*)(tp + 28);
    float4 u0 = *(const float4*)wp,        u1 = *(const float4*)(wp + 4);
    float4 u2 = *(const float4*)(wp + 8),  u3 = *(const float4*)(wp + 12);
    float4 u4 = *(const float4*)(wp + 16), u5 = *(const float4*)(wp + 20);
    float4 u6 = *(const float4*)(wp + 24), u7 = *(const float4*)(wp + 28);
    float p = t0.x * u0.x + t0.y * u0.y + t0.z * u0.z + t0.w * u0.w
            + t1.x * u1.x + t1.y * u1.y + t1.z * u1.z + t1.w * u1.w
            + t2.x * u2.x + t2.y * u2.y + t2.z * u2.z + t2.w * u2.w
            + t3.x * u3.x + t3.y * u3.y + t3.z * u3.z + t3.w * u3.w
            + t4.x * u4.x + t4.y * u4.y + t4.z * u4.z + t4.w * u4.w
            + t5.x * u5.x + t5.y * u5.y + t5.z * u5.z + t5.w * u5.w
            + t6.x * u6.x + t6.y * u6.y + t6.z * u6.z + t6.w * u6.w
            + t7.x * u7.x + t7.y * u7.y + t7.z * u7.z + t7.w * u7.w;
    p += __shfl_xor(p, 16, 64);         // combine the two K-halves
    if (hl < 16) h2b[(unsigned)n * NCLS + c] = f2bf(p * dn);
}

// ---------- fused layer-2 agg + epilogue ----------
// 8 nodes/wave (8 lanes each: 4 slots x 2 dim-lanes), flat-batch-32 + sentinel
__global__ __launch_bounds__(256) void agg2_fused(
        const int* __restrict__ row_ptr, const int* __restrict__ csr_src,
        const unsigned short* __restrict__ h2b, const float* __restrict__ dis,
        const float* __restrict__ b2, float* __restrict__ out, int N) {
    int t = blockIdx.x * 256 + threadIdx.x;
    int lane = t & 63;
    int grp = lane >> 3;         // node within wave (0..7)
    int gl = lane & 7;
    int slot = gl >> 1;          // edge slot 0..3
    int sub = gl & 1;            // dims sub*8 .. sub*8+7
    int n = (t >> 6) * 8 + grp;
    if (n >= N) return;          // uniform within each 8-lane group
    int beg = row_ptr[n];
    int end = row_ptr[n + 1];
    int i0 = beg + slot;
    int s0 = csr_src[i0];
    int s1 = csr_src[i0 + 4];
    int s2 = csr_src[i0 + 8];
    int s3 = csr_src[i0 + 12];
    int s4 = csr_src[i0 + 16];
    int s5 = csr_src[i0 + 20];
    int s6 = csr_src[i0 + 24];
    int s7 = csr_src[i0 + 28];
    s0 = (i0      < end) ? s0 : N;   // row N of h2b is zeros
    s1 = (i0 + 4  < end) ? s1 : N;
    s2 = (i0 + 8  < end) ? s2 : N;
    s3 = (i0 + 12 < end) ? s3 : N;
    s4 = (i0 + 16 < end) ? s4 : N;
    s5 = (i0 + 20 < end) ? s5 : N;
    s6 = (i0 + 24 < end) ? s6 : N;
    s7 = (i0 + 28 < end) ? s7 : N;
    const unsigned short* hp = h2b + sub * 8;
    uint4 v0 = *(const uint4*)(hp + (unsigned)s0 * NCLS);
    uint4 v1 = *(const uint4*)(hp + (unsigned)s1 * NCLS);
    uint4 v2 = *(const uint4*)(hp + (unsigned)s2 * NCLS);
    uint4 v3 = *(const uint4*)(hp + (unsigned)s3 * NCLS);
    uint4 v4 = *(const uint4*)(hp + (unsigned)s4 * NCLS);
    uint4 v5 = *(const uint4*)(hp + (unsigned)s5 * NCLS);
    uint4 v6 = *(const uint4*)(hp + (unsigned)s6 * NCLS);
    uint4 v7 = *(const uint4*)(hp + (unsigned)s7 * NCLS);
    f32x2 a0 = (bfpair(v0.x) + bfpair(v1.x)) + (bfpair(v2.x) + bfpair(v3.x));
    f32x2 a1 = (bfpair(v0.y) + bfpair(v1.y)) + (bfpair(v2.y) + bfpair(v3.y));
    f32x2 a2 = (bfpair(v0.z) + bfpair(v1.z)) + (bfpair(v2.z) + bfpair(v3.z));
    f32x2 a3 = (bfpair(v0.w) + bfpair(v1.w)) + (bfpair(v2.w) + bfpair(v3.w));
    a0 += (bfpair(v4.x) + bfpair(v5.x)) + (bfpair(v6.x) + bfpair(v7.x));
    a1 += (bfpair(v4.y) + bfpair(v5.y)) + (bfpair(v6.y) + bfpair(v7.y));
    a2 += (bfpair(v4.z) + bfpair(v5.z)) + (bfpair(v6.z) + bfpair(v7.z));
    a3 += (bfpair(v4.w) + bfpair(v5.w)) + (bfpair(v6.w) + bfpair(v7.w));
    for (int i = beg + 32 + slot; i < end; i += 4) {
        int s = csr_src[i];
        uint4 v = *(const uint4*)(hp + (unsigned)s * NCLS);
        a0 += bfpair(v.x);
        a1 += bfpair(v.y);
        a2 += bfpair(v.z);
        a3 += bfpair(v.w);
    }
    // reduce across 4 slots (lane bits 1,2 — stays inside the 8-lane group)
    #pragma unroll
    for (int m = 2; m <= 4; m <<= 1) {
        a0.x += __shfl_xor(a0.x, m, 64); a0.y += __shfl_xor(a0.y, m, 64);
        a1.x += __shfl_xor(a1.x, m, 64); a1.y += __shfl_xor(a1.y, m, 64);
        a2.x += __shfl_xor(a2.x, m, 64); a2.y += __shfl_xor(a2.y, m, 64);
        a3.x += __shfl_xor(a3.x, m, 64); a3.y += __shfl_xor(a3.y, m, 64);
    }
    if (slot == 0) {
        float dn = dis[n];
        float4 bl = ((const float4*)b2)[sub * 2];
        float4 bh = ((const float4*)b2)[sub * 2 + 1];
        float4 o0, o1;
        o0.x = fmaf(dn, a0.x, bl.x); o0.y = fmaf(dn, a0.y, bl.y);
        o0.z = fmaf(dn, a1.x, bl.z); o0.w = fmaf(dn, a1.y, bl.w);
        o1.x = fmaf(dn, a2.x, bh.x); o1.y = fmaf(dn, a2.y, bh.y);
        o1.z = fmaf(dn, a3.x, bh.z); o1.w = fmaf(dn, a3.y, bh.w);
        float* op = out + (unsigned)n * NCLS + sub * 8;
        *(float4*)op = o0;
        *(float4*)(op + 4) = o1;
    }
}

extern "C" void kernel_launch(void* const* d_in, const int* in_sizes, int n_in,
                              void* d_out, int out_size, void* d_ws, size_t ws_size,
                              hipStream_t stream) {
    const float* x   = (const float*)d_in[0];
    const int*   src = (const int*)  d_in[1];
    const int*   dst = (const int*)  d_in[2];
    const float* W1  = (const float*)d_in[3];
    const float* b1  = (const float*)d_in[4];
    const float* W2  = (const float*)d_in[5];
    const float* b2  = (const float*)d_in[6];
    float* out = (float*)d_out;
    int E = in_sizes[1];
    int N = in_sizes[0] / F_IN;
    int NB = (N + BNODES - 1) >> BSHIFT;
    int nchunks = (E + CHUNK - 1) / CHUNK;   // 208 for E=1.7M (col_scan requires <=256)

    char* ws = (char*)d_ws;
    size_t off = 0;
    auto alloc = [&](size_t bytes) { size_t o = off; off = (off + bytes + 255) & ~(size_t)255; return (void*)(ws + o); };
    int*   bucket_base   = (int*)  alloc((size_t)(NB + 1) * 4);
    int*   blk_hist      = (int*)  alloc((size_t)nchunks * NB * 4);
    int*   row_ptr       = (int*)  alloc((size_t)(N + 1) * 4);
    int*   csr_src       = (int*)  alloc((size_t)(E + 64) * 4);   // +64 slack for batch over-read
    float* dis           = (float*)alloc((size_t)N * 4);
    unsigned short* w1t  = (unsigned short*)alloc((size_t)F_IN * HID * 2);
    unsigned short* h1b  = (unsigned short*)alloc((size_t)(N + 1) * HID * 2);  // +1 sentinel row
    unsigned short* h2b  = (unsigned short*)alloc((size_t)(N + 1) * NCLS * 2); // +1 sentinel row
    // part[] aliases h1b: dead before gemm1 writes h1b (E*4 = 6.8MB <= (N+1)*HID*2 = 12.8MB)
    unsigned int* part   = (unsigned int*)h1b;

    hist_w1t_kernel<<<nchunks + 1, 256, 0, stream>>>(dst, blk_hist, W1, w1t, h2b, E, N, NB, nchunks);
    bucket_scan    <<<1, 512, 0, stream>>>(blk_hist, bucket_base, row_ptr, NB, N, E, nchunks);
    col_scan       <<<NB, 256, 0, stream>>>(blk_hist, bucket_base, NB, nchunks);
    scatter_kernel <<<nchunks, 256, 0, stream>>>(src, dst, blk_hist, part, E, NB);
    csr_build      <<<NB, 256, 0, stream>>>(part, bucket_base, csr_src, row_ptr, dis, N);
    gemm1_kernel   <<<(N + 64) / 64, 256, 0, stream>>>(x, w1t, dis, h1b, N);  // +1 covers row N
    agg1_fused     <<<(N + 7) / 8, 256, 0, stream>>>(row_ptr, csr_src, h1b, dis, b1, W2, h2b, N);
    agg2_fused     <<<(N + 31) / 32, 256, 0, stream>>>(row_ptr, csr_src, h2b, dis, b2, out, N);
}

// Round 8
// 207.487 us; speedup vs baseline: 1.9621x; 1.0120x over previous
//
#include <hip/hip_runtime.h>

#define F_IN 128
#define HID  64
#define NCLS 16

#define BSHIFT 8            // 256 nodes per bucket
#define BNODES 256
#define NB_MAX 512          // max buckets (N<=128k)
#define CHUNK  8192         // edges per partition block (nchunks must be <=256 for col_scan)
#define CAP    8192         // max edges per bucket in LDS (mean 4352, 50+ sigma margin)
#define PADB   772          // per-bucket padding slack: 256 rows * 3 + 4 (base align)

typedef __attribute__((ext_vector_type(2))) float f32x2;
typedef __attribute__((ext_vector_type(8))) short bf16x8;
typedef __attribute__((ext_vector_type(4))) float f32x4;

// round-to-nearest-even fp32 -> bf16
__device__ __forceinline__ unsigned short f2bf(float f) {
    unsigned int u = __float_as_uint(f);
    u += 0x7FFFu + ((u >> 16) & 1u);
    return (unsigned short)(u >> 16);
}
// one dword = 2 packed bf16 -> f32x2 (2 VALU unpack + packed add)
__device__ __forceinline__ f32x2 bfpair(unsigned int u) {
    f32x2 r;
    r.x = __uint_as_float(u << 16);
    r.y = __uint_as_float(u & 0xFFFF0000u);
    return r;
}

// ---------- pass 1: per-block bucket histogram (non-atomic global) + fused w1t ----------
__global__ __launch_bounds__(256) void hist_w1t_kernel(const int* __restrict__ dst,
                                                       int* __restrict__ blk_hist,
                                                       const float* __restrict__ W1,
                                                       unsigned short* __restrict__ w1t,
                                                       unsigned short* __restrict__ h2b,
                                                       int E, int N, int NB, int nchunks) {
    int blk = blockIdx.x;
    int tid = threadIdx.x;
    if (blk == nchunks) {           // fused W1 -> bf16 transpose block
        for (int i = tid; i < F_IN * HID; i += 256) {
            int k = i >> 6, n = i & 63;
            w1t[n * F_IN + k] = f2bf(W1[i]);
        }
        if (tid < NCLS) h2b[(size_t)N * NCLS + tid] = 0;   // zero sentinel row for agg2
        return;
    }
    __shared__ int hist[NB_MAX];
    for (int i = tid; i < NB; i += 256) hist[i] = 0;
    __syncthreads();
    int cb = blk * CHUNK;
    #pragma unroll
    for (int k = 0; k < CHUNK / 1024; k++) {
        int e = cb + (k * 256 + tid) * 4;
        if (e + 3 < E) {
            int4 d4 = *(const int4*)&dst[e];
            atomicAdd(&hist[d4.x >> BSHIFT], 1);
            atomicAdd(&hist[d4.y >> BSHIFT], 1);
            atomicAdd(&hist[d4.z >> BSHIFT], 1);
            atomicAdd(&hist[d4.w >> BSHIFT], 1);
        } else {
            for (int t = 0; t < 4; t++)
                if (e + t < E) atomicAdd(&hist[dst[e + t] >> BSHIFT], 1);
        }
    }
    __syncthreads();
    for (int i = tid; i < NB; i += 256) blk_hist[(size_t)blk * NB + i] = hist[i];
}

// ---------- pass 2: fused column-reduce + scan (single block, 512 threads) ----------
__global__ __launch_bounds__(512) void bucket_scan(const int* __restrict__ blk_hist,
                                                   int* __restrict__ bucket_base,
                                                   int NB, int E, int nchunks) {
    __shared__ int s[512];
    int tid = threadIdx.x;
    int v = 0;
    if (tid < NB) {
        #pragma unroll 4
        for (int j = 0; j < nchunks; j++) v += blk_hist[(size_t)j * NB + tid];
    }
    s[tid] = v;
    __syncthreads();
    for (int off = 1; off < 512; off <<= 1) {
        int t = (tid >= off) ? s[tid - off] : 0;
        __syncthreads();
        s[tid] += t;
        __syncthreads();
    }
    if (tid < NB) bucket_base[tid] = s[tid] - v;
    if (tid == 0) bucket_base[NB] = E;
}

// ---------- pass 2c: per-bucket parallel column scan -> absolute per-chunk bases ----------
__global__ __launch_bounds__(256) void col_scan(int* __restrict__ blk_hist,
                                                const int* __restrict__ bucket_base,
                                                int NB, int nchunks) {
    __shared__ int s[256];
    int b = blockIdx.x;
    int tid = threadIdx.x;
    int v = (tid < nchunks) ? blk_hist[(size_t)tid * NB + b] : 0;
    s[tid] = v;
    __syncthreads();
    for (int off = 1; off < 256; off <<= 1) {
        int t = (tid >= off) ? s[tid - off] : 0;
        __syncthreads();
        s[tid] += t;
        __syncthreads();
    }
    if (tid < nchunks) blk_hist[(size_t)tid * NB + b] = s[tid] - v + bucket_base[b];
}

// ---------- pass 3: single-pass partition (LDS cursors, coalesced per-bucket runs) ----------
__global__ __launch_bounds__(256) void scatter_kernel(const int* __restrict__ src,
                                                      const int* __restrict__ dst,
                                                      const int* __restrict__ blk_hist,
                                                      unsigned int* __restrict__ part,
                                                      int E, int NB) {
    __shared__ int cur[NB_MAX];
    int tid = threadIdx.x;
    int blk = blockIdx.x;
    for (int i = tid; i < NB; i += 256) cur[i] = blk_hist[(size_t)blk * NB + i];
    __syncthreads();
    int cb = blk * CHUNK;
    #pragma unroll
    for (int k = 0; k < CHUNK / 1024; k++) {
        int e = cb + (k * 256 + tid) * 4;
        if (e + 3 < E) {
            int4 d4 = *(const int4*)&dst[e];
            int4 s4 = *(const int4*)&src[e];
            int p0 = atomicAdd(&cur[d4.x >> BSHIFT], 1);
            part[p0] = ((unsigned int)(d4.x & (BNODES - 1)) << 24) | (unsigned int)s4.x;
            int p1 = atomicAdd(&cur[d4.y >> BSHIFT], 1);
            part[p1] = ((unsigned int)(d4.y & (BNODES - 1)) << 24) | (unsigned int)s4.y;
            int p2 = atomicAdd(&cur[d4.z >> BSHIFT], 1);
            part[p2] = ((unsigned int)(d4.z & (BNODES - 1)) << 24) | (unsigned int)s4.z;
            int p3 = atomicAdd(&cur[d4.w >> BSHIFT], 1);
            part[p3] = ((unsigned int)(d4.w & (BNODES - 1)) << 24) | (unsigned int)s4.w;
        } else {
            for (int t = 0; t < 4; t++)
                if (e + t < E) {
                    int d = dst[e + t];
                    int pos = atomicAdd(&cur[d >> BSHIFT], 1);
                    part[pos] = ((unsigned int)(d & (BNODES - 1)) << 24) | (unsigned int)src[e + t];
                }
        }
    }
}

// ---------- pass 4: per-bucket counting sort -> PADDED csr (rows 4-aligned, sentinel N) ----------
__global__ __launch_bounds__(256) void csr_build(const unsigned int* __restrict__ part,
                                                 const int* __restrict__ bucket_base,
                                                 int* __restrict__ csr_src,
                                                 int* __restrict__ row_ptr,
                                                 int* __restrict__ row_len,
                                                 float* __restrict__ dis,
                                                 int N) {
    __shared__ unsigned int eL[CAP];
    __shared__ unsigned int outL[CAP + PADB];
    __shared__ int cnt[BNODES];
    __shared__ int sc[BNODES];
    __shared__ int cur[BNODES];
    int tid = threadIdx.x;
    int b = blockIdx.x;
    int eB = bucket_base[b];
    int eN = bucket_base[b + 1] - eB;
    if (eN > CAP) eN = CAP;
    int pb = (eB + b * PADB + 3) & ~3;   // 4-aligned padded bucket base

    cnt[tid] = 0;
    __syncthreads();
    for (int i = tid; i < eN; i += 256) {
        unsigned int v = part[eB + i];
        eL[i] = v;
        atomicAdd(&cnt[v >> 24], 1);
    }
    // sentinel-init the padded output region (real edges overwrite below)
    for (int i = tid; i < eN + PADB; i += 256) outL[i] = (unsigned int)N;
    __syncthreads();
    int myc = cnt[tid];
    int pd = (myc + 3) & ~3;        // padded row length (multiple of 4)
    sc[tid] = pd;
    __syncthreads();
    for (int off = 1; off < 256; off <<= 1) {
        int t = (tid >= off) ? sc[tid - off] : 0;
        __syncthreads();
        sc[tid] += t;
        __syncthreads();
    }
    int excl = sc[tid] - pd;        // multiple of 4
    cur[tid] = excl;
    int gnode = b * BNODES + tid;
    if (gnode < N) {
        row_ptr[gnode] = pb + excl;  // 4-aligned: pb aligned + excl mult of 4
        row_len[gnode] = pd;
        float d = (float)myc;
        dis[gnode] = d > 0.0f ? rsqrtf(fmaxf(d, 1.0f)) : 0.0f;
    }
    __syncthreads();
    int pTot = sc[BNODES - 1];      // padded bucket total (<= eN + PADB)
    for (int i = tid; i < eN; i += 256) {
        unsigned int v = eL[i];
        int pos = atomicAdd(&cur[v >> 24], 1);
        outL[pos] = v & 0xFFFFFFu;
    }
    __syncthreads();
    for (int i = tid; i < pTot; i += 256)
        csr_src[pb + i] = (int)outL[i];
}

// ---------- gemm1 via MFMA bf16: 64 rows/block; also emits zeroed sentinel row N ----------
__global__ __launch_bounds__(256) void gemm1_kernel(
        const float* __restrict__ x, const unsigned short* __restrict__ w1t,
        const float* __restrict__ dis, unsigned short* __restrict__ h1b, int N) {
    __shared__ unsigned short xs[64][136];
    __shared__ unsigned short wsb[64][136];
    __shared__ float diss[64];
    int tid = threadIdx.x;
    int w = tid >> 6;
    int lane = tid & 63;
    int row0 = blockIdx.x * 64;

    #pragma unroll
    for (int it = 0; it < 8; it++) {
        int f = it * 256 + tid;
        int r = f >> 5, c = f & 31;
        float4 v = make_float4(0.f, 0.f, 0.f, 0.f);
        if (row0 + r < N) v = ((const float4*)x)[(size_t)(row0 + r) * 32 + c];
        unsigned int p0 = (unsigned int)f2bf(v.x) | ((unsigned int)f2bf(v.y) << 16);
        unsigned int p1 = (unsigned int)f2bf(v.z) | ((unsigned int)f2bf(v.w) << 16);
        *(uint2*)&xs[r][c * 4] = make_uint2(p0, p1);
    }
    #pragma unroll
    for (int it = 0; it < 4; it++) {
        int f = it * 256 + tid;
        int r = f >> 4, c = f & 15;
        *(uint4*)&wsb[r][c * 8] = ((const uint4*)w1t)[f];
    }
    if (tid < 64) diss[tid] = (row0 + tid < N) ? dis[row0 + tid] : 0.f;
    __syncthreads();

    int q = lane >> 4;
    int l15 = lane & 15;
    f32x4 acc[4] = {{0,0,0,0},{0,0,0,0},{0,0,0,0},{0,0,0,0}};
    bf16x8 a[4];
    #pragma unroll
    for (int kk = 0; kk < 4; kk++)
        a[kk] = *(const bf16x8*)&xs[w * 16 + l15][kk * 32 + q * 8];
    #pragma unroll
    for (int kk = 0; kk < 4; kk++) {
        #pragma unroll
        for (int ct = 0; ct < 4; ct++) {
            bf16x8 b = *(const bf16x8*)&wsb[ct * 16 + l15][kk * 32 + q * 8];
            acc[ct] = __builtin_amdgcn_mfma_f32_16x16x32_bf16(a[kk], b, acc[ct], 0, 0, 0);
        }
    }
    __syncthreads();
    #pragma unroll
    for (int ct = 0; ct < 4; ct++) {
        #pragma unroll
        for (int r = 0; r < 4; r++) {
            int m = w * 16 + q * 4 + r;
            xs[m][ct * 16 + l15] = f2bf(acc[ct][r] * diss[m]);
        }
    }
    __syncthreads();
    #pragma unroll
    for (int it = 0; it < 2; it++) {
        int f = it * 256 + tid;
        int r = f >> 3, c = f & 7;
        if (row0 + r < N + 1)   // row N written as zeros (diss=0) -> gather sentinel
            ((uint4*)&h1b[(size_t)(row0 + r) * HID])[c] = *(const uint4*)&xs[r][c * 8];
    }
}

// ---------- fused layer-1 agg + ReLU + W2 GEMM ----------
// 2 nodes/wave (half-wave each: 4 slots x 8 dim-lanes); padded CSR rows (4-aligned):
// 2 int4 index loads + 2 vector sentinel-selects + 8 independent 16B gathers per lane.
__global__ __launch_bounds__(256) void agg1_fused(
        const int* __restrict__ row_ptr, const int* __restrict__ row_len,
        const int* __restrict__ csr_src,
        const unsigned short* __restrict__ h1b, const float* __restrict__ dis,
        const float* __restrict__ b1, const float* __restrict__ W2,
        unsigned short* __restrict__ h2b, int N) {
    __shared__ float W2t[NCLS][HID + 4];   // transposed, padded row stride 68
    __shared__ float ts[8][HID];
    int tid = threadIdx.x;
    int w = tid >> 6;
    int lane = tid & 63;
    int half = lane >> 5;      // node within wave
    int hl = lane & 31;        // lane within half
    int sub = hl & 7;          // dims sub*8 .. sub*8+7 (16B)
    int slot = hl >> 3;        // edge slot 0..3 (each owns 2 int4 runs)
    int n = blockIdx.x * 8 + w * 2 + half;
    int nc = (n < N) ? n : 0;  // clamp so tail lanes still load safely

    // issue row_ptr/row_len/dis + vector index loads BEFORE LDS staging
    int start = row_ptr[nc];   // 4-aligned by construction
    int plen = row_len[nc];    // multiple of 4
    float dn = dis[nc];
    const int4* ip = (const int4*)(csr_src + start);
    int4 q0 = ip[2 * slot];
    int4 q1 = ip[2 * slot + 1];

    for (int i = tid; i < HID * NCLS; i += 256) W2t[i & 15][i >> 4] = W2[i];
    __syncthreads();
    if (n >= N) return;        // after the only __syncthreads (no barrier below)

    // vector sentinel-select: plen % 4 == 0, one compare covers a whole int4
    int e0 = slot * 8;
    if (e0 >= plen)     q0 = make_int4(N, N, N, N);
    if (e0 + 4 >= plen) q1 = make_int4(N, N, N, N);
    const unsigned short* hp = h1b + sub * 8;
    uint4 v0 = *(const uint4*)(hp + (unsigned)q0.x * HID);
    uint4 v1 = *(const uint4*)(hp + (unsigned)q0.y * HID);
    uint4 v2 = *(const uint4*)(hp + (unsigned)q0.z * HID);
    uint4 v3 = *(const uint4*)(hp + (unsigned)q0.w * HID);
    uint4 v4 = *(const uint4*)(hp + (unsigned)q1.x * HID);
    uint4 v5 = *(const uint4*)(hp + (unsigned)q1.y * HID);
    uint4 v6 = *(const uint4*)(hp + (unsigned)q1.z * HID);
    uint4 v7 = *(const uint4*)(hp + (unsigned)q1.w * HID);
    f32x2 a0 = (bfpair(v0.x) + bfpair(v1.x)) + (bfpair(v2.x) + bfpair(v3.x));
    f32x2 a1 = (bfpair(v0.y) + bfpair(v1.y)) + (bfpair(v2.y) + bfpair(v3.y));
    f32x2 a2 = (bfpair(v0.z) + bfpair(v1.z)) + (bfpair(v2.z) + bfpair(v3.z));
    f32x2 a3 = (bfpair(v0.w) + bfpair(v1.w)) + (bfpair(v2.w) + bfpair(v3.w));
    a0 += (bfpair(v4.x) + bfpair(v5.x)) + (bfpair(v6.x) + bfpair(v7.x));
    a1 += (bfpair(v4.y) + bfpair(v5.y)) + (bfpair(v6.y) + bfpair(v7.y));
    a2 += (bfpair(v4.z) + bfpair(v5.z)) + (bfpair(v6.z) + bfpair(v7.z));
    a3 += (bfpair(v4.w) + bfpair(v5.w)) + (bfpair(v6.w) + bfpair(v7.w));
    // residual for rare rows with plen > 32 (sentinel entries included, harmless)
    for (int i = 32 + slot; i < plen; i += 4) {
        int s = csr_src[start + i];
        uint4 v = *(const uint4*)(hp + (unsigned)s * HID);
        a0 += bfpair(v.x);
        a1 += bfpair(v.y);
        a2 += bfpair(v.z);
        a3 += bfpair(v.w);
    }
    // reduce across the 4 slots (lane bits 3,4 — stays within the half)
    #pragma unroll
    for (int m = 8; m <= 16; m <<= 1) {
        a0.x += __shfl_xor(a0.x, m, 64); a0.y += __shfl_xor(a0.y, m, 64);
        a1.x += __shfl_xor(a1.x, m, 64); a1.y += __shfl_xor(a1.y, m, 64);
        a2.x += __shfl_xor(a2.x, m, 64); a2.y += __shfl_xor(a2.y, m, 64);
        a3.x += __shfl_xor(a3.x, m, 64); a3.y += __shfl_xor(a3.y, m, 64);
    }
    if (slot == 0) {
        float4 bl = ((const float4*)b1)[sub * 2];
        float4 bh = ((const float4*)b1)[sub * 2 + 1];
        float4 r0, r1;
        r0.x = fmaxf(fmaf(dn, a0.x, bl.x), 0.f);
        r0.y = fmaxf(fmaf(dn, a0.y, bl.y), 0.f);
        r0.z = fmaxf(fmaf(dn, a1.x, bl.z), 0.f);
        r0.w = fmaxf(fmaf(dn, a1.y, bl.w), 0.f);
        r1.x = fmaxf(fmaf(dn, a2.x, bh.x), 0.f);
        r1.y = fmaxf(fmaf(dn, a2.y, bh.y), 0.f);
        r1.z = fmaxf(fmaf(dn, a3.x, bh.z), 0.f);
        r1.w = fmaxf(fmaf(dn, a3.y, bh.w), 0.f);
        *(float4*)&ts[w * 2 + half][sub * 8] = r0;
        *(float4*)&ts[w * 2 + half][sub * 8 + 4] = r1;
    }
    // wave-local LDS round-trip (same wave writes+reads; compiler inserts lgkmcnt)
    int q = hl >> 4, c = hl & 15;       // q: K-half 0/1, c: output class
    const float* tp = &ts[w * 2 + half][q * 32];
    const float* wp = &W2t[c][q * 32];
    float4 t0 = *(const float4*)tp,        t1 = *(const float4*)(tp + 4);
    float4 t2 = *(const float4*)(tp + 8),  t3 = *(const float4*)(tp + 12);
    float4 t4 = *(const float4*)(tp + 16), t5 = *(const float4*)(tp + 20);
    float4 t6 = *(const float4*)(tp + 24), t7 = *(const float4*)(tp + 28);
    float4 u0 = *(const float4*)wp,        u1 = *(const float4*)(wp + 4);
    float4 u2 = *(const float4*)(wp + 8),  u3 = *(const float4*)(wp + 12);
    float4 u4 = *(const float4*)(wp + 16), u5 = *(const float4*)(wp + 20);
    float4 u6 = *(const float4*)(wp + 24), u7 = *(const float4*)(wp + 28);
    float p = t0.x * u0.x + t0.y * u0.y + t0.z * u0.z + t0.w * u0.w
            + t1.x * u1.x + t1.y * u1.y + t1.z * u1.z + t1.w * u1.w
            + t2.x * u2.x + t2.y * u2.y + t2.z * u2.z + t2.w * u2.w
            + t3.x * u3.x + t3.y * u3.y + t3.z * u3.z + t3.w * u3.w
            + t4.x * u4.x + t4.y * u4.y + t4.z * u4.z + t4.w * u4.w
            + t5.x * u5.x + t5.y * u5.y + t5.z * u5.z + t5.w * u5.w
            + t6.x * u6.x + t6.y * u6.y + t6.z * u6.z + t6.w * u6.w
            + t7.x * u7.x + t7.y * u7.y + t7.z * u7.z + t7.w * u7.w;
    p += __shfl_xor(p, 16, 64);         // combine the two K-halves
    if (hl < 16) h2b[(unsigned)n * NCLS + c] = f2bf(p * dn);
}

// ---------- fused layer-2 agg + epilogue ----------
// 8 nodes/wave (8 lanes each: 4 slots x 2 dim-lanes), padded CSR + int4 index loads
__global__ __launch_bounds__(256) void agg2_fused(
        const int* __restrict__ row_ptr, const int* __restrict__ row_len,
        const int* __restrict__ csr_src,
        const unsigned short* __restrict__ h2b, const float* __restrict__ dis,
        const float* __restrict__ b2, float* __restrict__ out, int N) {
    int t = blockIdx.x * 256 + threadIdx.x;
    int lane = t & 63;
    int grp = lane >> 3;         // node within wave (0..7)
    int gl = lane & 7;
    int slot = gl >> 1;          // edge slot 0..3
    int sub = gl & 1;            // dims sub*8 .. sub*8+7
    int n = (t >> 6) * 8 + grp;
    if (n >= N) return;          // uniform within each 8-lane group
    int start = row_ptr[n];
    int plen = row_len[n];
    const int4* ip = (const int4*)(csr_src + start);
    int4 q0 = ip[2 * slot];
    int4 q1 = ip[2 * slot + 1];
    int e0 = slot * 8;
    if (e0 >= plen)     q0 = make_int4(N, N, N, N);
    if (e0 + 4 >= plen) q1 = make_int4(N, N, N, N);
    const unsigned short* hp = h2b + sub * 8;
    uint4 v0 = *(const uint4*)(hp + (unsigned)q0.x * NCLS);
    uint4 v1 = *(const uint4*)(hp + (unsigned)q0.y * NCLS);
    uint4 v2 = *(const uint4*)(hp + (unsigned)q0.z * NCLS);
    uint4 v3 = *(const uint4*)(hp + (unsigned)q0.w * NCLS);
    uint4 v4 = *(const uint4*)(hp + (unsigned)q1.x * NCLS);
    uint4 v5 = *(const uint4*)(hp + (unsigned)q1.y * NCLS);
    uint4 v6 = *(const uint4*)(hp + (unsigned)q1.z * NCLS);
    uint4 v7 = *(const uint4*)(hp + (unsigned)q1.w * NCLS);
    f32x2 a0 = (bfpair(v0.x) + bfpair(v1.x)) + (bfpair(v2.x) + bfpair(v3.x));
    f32x2 a1 = (bfpair(v0.y) + bfpair(v1.y)) + (bfpair(v2.y) + bfpair(v3.y));
    f32x2 a2 = (bfpair(v0.z) + bfpair(v1.z)) + (bfpair(v2.z) + bfpair(v3.z));
    f32x2 a3 = (bfpair(v0.w) + bfpair(v1.w)) + (bfpair(v2.w) + bfpair(v3.w));
    a0 += (bfpair(v4.x) + bfpair(v5.x)) + (bfpair(v6.x) + bfpair(v7.x));
    a1 += (bfpair(v4.y) + bfpair(v5.y)) + (bfpair(v6.y) + bfpair(v7.y));
    a2 += (bfpair(v4.z) + bfpair(v5.z)) + (bfpair(v6.z) + bfpair(v7.z));
    a3 += (bfpair(v4.w) + bfpair(v5.w)) + (bfpair(v6.w) + bfpair(v7.w));
    for (int i = 32 + slot; i < plen; i += 4) {
        int s = csr_src[start + i];
        uint4 v = *(const uint4*)(hp + (unsigned)s * NCLS);
        a0 += bfpair(v.x);
        a1 += bfpair(v.y);
        a2 += bfpair(v.z);
        a3 += bfpair(v.w);
    }
    // reduce across 4 slots (lane bits 1,2 — stays inside the 8-lane group)
    #pragma unroll
    for (int m = 2; m <= 4; m <<= 1) {
        a0.x += __shfl_xor(a0.x, m, 64); a0.y += __shfl_xor(a0.y, m, 64);
        a1.x += __shfl_xor(a1.x, m, 64); a1.y += __shfl_xor(a1.y, m, 64);
        a2.x += __shfl_xor(a2.x, m, 64); a2.y += __shfl_xor(a2.y, m, 64);
        a3.x += __shfl_xor(a3.x, m, 64); a3.y += __shfl_xor(a3.y, m, 64);
    }
    if (slot == 0) {
        float dn = dis[n];
        float4 bl = ((const float4*)b2)[sub * 2];
        float4 bh = ((const float4*)b2)[sub * 2 + 1];
        float4 o0, o1;
        o0.x = fmaf(dn, a0.x, bl.x); o0.y = fmaf(dn, a0.y, bl.y);
        o0.z = fmaf(dn, a1.x, bl.z); o0.w = fmaf(dn, a1.y, bl.w);
        o1.x = fmaf(dn, a2.x, bh.x); o1.y = fmaf(dn, a2.y, bh.y);
        o1.z = fmaf(dn, a3.x, bh.z); o1.w = fmaf(dn, a3.y, bh.w);
        float* op = out + (unsigned)n * NCLS + sub * 8;
        *(float4*)op = o0;
        *(float4*)(op + 4) = o1;
    }
}

extern "C" void kernel_launch(void* const* d_in, const int* in_sizes, int n_in,
                              void* d_out, int out_size, void* d_ws, size_t ws_size,
                              hipStream_t stream) {
    const float* x   = (const float*)d_in[0];
    const int*   src = (const int*)  d_in[1];
    const int*   dst = (const int*)  d_in[2];
    const float* W1  = (const float*)d_in[3];
    const float* b1  = (const float*)d_in[4];
    const float* W2  = (const float*)d_in[5];
    const float* b2  = (const float*)d_in[6];
    float* out = (float*)d_out;
    int E = in_sizes[1];
    int N = in_sizes[0] / F_IN;
    int NB = (N + BNODES - 1) >> BSHIFT;
    int nchunks = (E + CHUNK - 1) / CHUNK;   // 208 for E=1.7M (col_scan requires <=256)

    char* ws = (char*)d_ws;
    size_t off = 0;
    auto alloc = [&](size_t bytes) { size_t o = off; off = (off + bytes + 255) & ~(size_t)255; return (void*)(ws + o); };
    int*   bucket_base   = (int*)  alloc((size_t)(NB + 1) * 4);
    int*   blk_hist      = (int*)  alloc((size_t)nchunks * NB * 4);
    int*   row_ptr       = (int*)  alloc((size_t)(N + 1) * 4);
    int*   row_len       = (int*)  alloc((size_t)N * 4);
    int*   csr_src       = (int*)  alloc((size_t)(E + (size_t)NB * PADB + 64) * 4);  // padded CSR
    float* dis           = (float*)alloc((size_t)N * 4);
    unsigned short* w1t  = (unsigned short*)alloc((size_t)F_IN * HID * 2);
    unsigned short* h1b  = (unsigned short*)alloc((size_t)(N + 1) * HID * 2);  // +1 sentinel row
    unsigned short* h2b  = (unsigned short*)alloc((size_t)(N + 1) * NCLS * 2); // +1 sentinel row
    // part[] aliases h1b: dead before gemm1 writes h1b (E*4 = 6.8MB <= (N+1)*HID*2 = 12.8MB)
    unsigned int* part   = (unsigned int*)h1b;

    hist_w1t_kernel<<<nchunks + 1, 256, 0, stream>>>(dst, blk_hist, W1, w1t, h2b, E, N, NB, nchunks);
    bucket_scan    <<<1, 512, 0, stream>>>(blk_hist, bucket_base, NB, E, nchunks);
    col_scan       <<<NB, 256, 0, stream>>>(blk_hist, bucket_base, NB, nchunks);
    scatter_kernel <<<nchunks, 256, 0, stream>>>(src, dst, blk_hist, part, E, NB);
    csr_build      <<<NB, 256, 0, stream>>>(part, bucket_base, csr_src, row_ptr, row_len, dis, N);
    gemm1_kernel   <<<(N + 64) / 64, 256, 0, stream>>>(x, w1t, dis, h1b, N);  // +1 covers row N
    agg1_fused     <<<(N + 7) / 8, 256, 0, stream>>>(row_ptr, row_len, csr_src, h1b, dis, b1, W2, h2b, N);
    agg2_fused     <<<(N + 31) / 32, 256, 0, stream>>>(row_ptr, row_len, csr_src, h2b, dis, b2, out, N);
}